// Round 1
// baseline (459.055 us; speedup 1.0000x reference)
//
#include <hip/hip_runtime.h>
#include <hip/hip_bf16.h>

typedef unsigned short ushort_t;
typedef __attribute__((ext_vector_type(4))) float floatx4;
typedef __attribute__((ext_vector_type(8))) __bf16 bf16x8;
typedef __attribute__((ext_vector_type(4))) unsigned short ushortx4;
typedef __attribute__((ext_vector_type(8))) unsigned short ushortx8;

// ---------- bf16 helpers ----------
static __device__ __forceinline__ float b2f(ushort_t u) {
  union { unsigned int i; float f; } v; v.i = ((unsigned int)u) << 16; return v.f;
}
static __device__ __forceinline__ ushort_t f2b(float f) {
  unsigned int x = __float_as_uint(f);
  unsigned int r = (x + 0x7fffu + ((x >> 16) & 1u)) >> 16;
  return (ushort_t)r;
}
// async global->LDS, 16B per lane (dest = wave-uniform base + lane*16)
static __device__ __forceinline__ void glds16(const ushort_t* g, ushort_t* l) {
  __builtin_amdgcn_global_load_lds(
      (const __attribute__((address_space(1))) unsigned int*)g,
      (__attribute__((address_space(3))) unsigned int*)l, 16, 0, 0);
}

// =========================================================================
// GEMM: C[M,N] = A[M,K] @ B[N,K]^T (+bias[col]).  Single-plane bf16 MFMA.
// LDS bank-conflict fix: k-chunk XOR swizzle. LDS slot (row, c) holds the
// global 16B k-chunk (c ^ (row&7)); rows stay contiguous (glds16-safe) and
// fragment reads (16 rows @ one k-chunk) spread over all 8 slots -> 2
// lanes/bank = conflict-free.
// XCD swizzle: lin = y*gridX+x; m = lin%gridY, n = lin/gridY.
// KS: split-K ways (1/2); blockIdx.z = z*KS+kq; partial kq -> Cout[kq].
// MODE 1: bf16 row-major (+z*cBatch)
// MODE 2: bf16 TRANSPOSED batched: [(b*N+col)*1024 + (m&1023)], b=m>>10
// Block 256 = 4 waves; tile 128x128xBK64; wave 64x64 via 4x4 mfma 16x16x32.
// =========================================================================
template<int MODE, bool ASPLIT, int KS>
__global__ __launch_bounds__(256, 3) void gemm_bt(
    const void* __restrict__ Ap, const ushort_t* __restrict__ Bm,
    const float* __restrict__ bias,
    ushort_t* __restrict__ C0, ushort_t* __restrict__ C1,
    ushort_t* __restrict__ C2, ushort_t* __restrict__ C3,
    int M, int N, int K, long aBatch, long bBatch, long cBatch)
{
  __shared__ __align__(16) ushort_t As[128 * 64];
  __shared__ __align__(16) ushort_t Bs[128 * 64];

  const int tid  = threadIdx.x;
  const int wid  = tid >> 6;
  const int lane = tid & 63;
  const int quad = lane >> 4;
  const int l16  = lane & 15;
  const int lin = blockIdx.y * gridDim.x + blockIdx.x;
  const int m0 = (lin % gridDim.y) * 128;
  const int n0 = (lin / gridDim.y) * 128;
  const int z  = (KS > 1) ? (int)(blockIdx.z / KS) : blockIdx.z;
  const int kq = (KS > 1) ? (int)(blockIdx.z % KS) : 0;
  const int kbeg = kq * (K / KS);
  const int kend = kbeg + (K / KS);
  ushort_t* outB = C0;
  if (KS >= 2 && kq == 1) outB = C1;
  if (KS >= 4 && kq == 2) outB = C2;
  if (KS >= 4 && kq == 3) outB = C3;

  const ushort_t* Ab = (const ushort_t*)Ap + (long)z * aBatch;
  const float*    Af = (const float*)Ap + (long)z * aBatch;
  Bm += (long)z * bBatch;

  const int wr = (wid >> 1) * 64;
  const int wc = (wid & 1) * 64;

  // staging: thread covers LDS slot (srow, tid&7); global source chunk is
  // XOR-swizzled: scj = (tid&7) ^ (srow&7)
  const int srow = tid >> 3;
  const int scj  = ((tid & 7) ^ (srow & 7)) * 8;
  const long abase = (long)(m0 + srow) * K + scj;
  const long bbase = (long)(n0 + srow) * K + scj;

  floatx4 acc[4][4];
#pragma unroll
  for (int i = 0; i < 4; ++i)
#pragma unroll
    for (int j = 0; j < 4; ++j) acc[i][j] = (floatx4){0.f, 0.f, 0.f, 0.f};

  const int rx = l16 & 7;   // row&7 for all fragment rows (wr,wc,i*16 mult 8)

  for (int k0 = kbeg; k0 < kend; k0 += 64) {
    __syncthreads();
    if constexpr (ASPLIT) {
#pragma unroll
      for (int p = 0; p < 4; ++p)
        glds16(Ab + abase + 32 * p * (long)K + k0, &As[tid * 8 + p * 2048]);
    } else {
#pragma unroll
      for (int p = 0; p < 8; ++p) {
        int c = tid + p * 256;
        int row = c >> 4, sub4 = c & 15;
        floatx4 va = *(const floatx4*)(Af + (long)(m0 + row) * K + k0 + sub4 * 4);
        ushortx4 ah;
#pragma unroll
        for (int r = 0; r < 4; ++r) ah[r] = f2b(va[r]);
        int dst = row * 64 + (((sub4 >> 1) ^ (row & 7)) << 3) + ((sub4 & 1) << 2);
        *(ushortx4*)(&As[dst]) = ah;
      }
    }
#pragma unroll
    for (int p = 0; p < 4; ++p)
      glds16(Bm + bbase + 32 * p * (long)K + k0, &Bs[tid * 8 + p * 2048]);
    __syncthreads();

#pragma unroll
    for (int kk = 0; kk < 2; ++kk) {
      bf16x8 a[4], b[4];
#pragma unroll
      for (int i = 0; i < 4; ++i)
        a[i] = *(const bf16x8*)(&As[(wr + i * 16 + l16) * 64 +
                                    (((kk * 4 + quad) ^ rx) << 3)]);
#pragma unroll
      for (int j = 0; j < 4; ++j)
        b[j] = *(const bf16x8*)(&Bs[(wc + j * 16 + l16) * 64 +
                                    (((kk * 4 + quad) ^ rx) << 3)]);
#pragma unroll
      for (int i = 0; i < 4; ++i)
#pragma unroll
        for (int j = 0; j < 4; ++j)
          acc[i][j] = __builtin_amdgcn_mfma_f32_16x16x32_bf16(a[i], b[j], acc[i][j], 0, 0, 0);
    }
  }

  // epilogue: lane = col l16; rows quad*4+r in each 16x16 sub-tile
#pragma unroll
  for (int j = 0; j < 4; ++j) {
    int col = n0 + wc + j * 16 + l16;
    float bv = (bias != nullptr) ? bias[col] : 0.f;
#pragma unroll
    for (int i = 0; i < 4; ++i) {
      int mbase = m0 + wr + i * 16 + quad * 4;
      if constexpr (MODE == 1) {
#pragma unroll
        for (int r = 0; r < 4; ++r)
          outB[(long)z * cBatch + (long)(mbase + r) * N + col] = f2b(acc[i][j][r] + bv);
      } else {
        int b = mbase >> 10, jrow = mbase & 1023;
        ushortx4 pk;
#pragma unroll
        for (int r = 0; r < 4; ++r) pk[r] = f2b(acc[i][j][r] + bv);
        *(ushortx4*)(outB + ((long)b * N + col) * 1024 + jrow) = pk;
      }
    }
  }
}

// =========================================================================
// prep (one dispatch): fp32->bf16 conversions, Wout transpose, Wemb
// transpose, bfused, layer-0 folded bias.
// blocks: [0,1152) Win | [1152,1216) Wemb | [1216,1600) Wconv |
// [1600,5696) ADJ | [5696,5888) WoutT | [5888,5920) WembT |
// [5920,6304) bfuse | [6304,6688) bfq
// =========================================================================
__global__ __launch_bounds__(256) void prep_kernel(
    const float* __restrict__ Win,  ushort_t* __restrict__ Winb,
    const float* __restrict__ Wemb, ushort_t* __restrict__ Wembb,
    const float* __restrict__ Wconv, ushort_t* __restrict__ Wcb,
    const float* __restrict__ ADJ,  ushort_t* __restrict__ ADJb,
    const float* __restrict__ Wout, ushort_t* __restrict__ WoT,
    const float* __restrict__ bout, const float* __restrict__ bconv,
    float* __restrict__ bfused,
    ushort_t* __restrict__ WembT,
    const float* __restrict__ bemb, const float* __restrict__ bin0,
    float* __restrict__ bfq)
{
  __shared__ float tile[64][65];
  const int bid = blockIdx.x, tid = threadIdx.x;
  if (bid < 5696) {
    const float* src; ushort_t* dst; long i;
    if (bid < 1152)      { src = Win;   dst = Winb;  i = (long)bid * 256 + tid; }
    else if (bid < 1216) { src = Wemb;  dst = Wembb; i = (long)(bid - 1152) * 256 + tid; }
    else if (bid < 1600) { src = Wconv; dst = Wcb;   i = (long)(bid - 1216) * 256 + tid; }
    else                 { src = ADJ;   dst = ADJb;  i = (long)(bid - 1600) * 256 + tid; }
    floatx4 a = ((const floatx4*)src)[2 * i];
    floatx4 b = ((const floatx4*)src)[2 * i + 1];
    ushortx4 ha, hb;
#pragma unroll
    for (int r = 0; r < 4; ++r) { ha[r] = f2b(a[r]); hb[r] = f2b(b[r]); }
    ((ushortx4*)dst)[2 * i] = ha; ((ushortx4*)dst)[2 * i + 1] = hb;
  } else if (bid < 5888) {
    // transpose+cvt: T[l][k][j] = bf16(Wout[l][j][k])
    const int t = bid - 5696;
    const int z = t >> 6, k0 = ((t >> 3) & 7) * 64, j0 = (t & 7) * 64;
    const long base = (long)z * 262144;
#pragma unroll
    for (int p = 0; p < 16; ++p) {
      int idx = tid + p * 256;
      int jj = idx >> 6, kk = idx & 63;
      tile[jj][kk] = Wout[base + (long)(j0 + jj) * 512 + k0 + kk];
    }
    __syncthreads();
#pragma unroll
    for (int p = 0; p < 16; ++p) {
      int idx = tid + p * 256;
      int kk = idx >> 6, jj = idx & 63;
      WoT[base + (long)(k0 + kk) * 512 + j0 + jj] = f2b(tile[jj][kk]);
    }
  } else if (bid < 5920) {
    // WembT[c][h] = bf16(Wemb[h][c])  (Wemb is [512][256])
    const int t = bid - 5888;
    const int j0 = (t >> 2) * 64, k0 = (t & 3) * 64;
#pragma unroll
    for (int p = 0; p < 16; ++p) {
      int idx = tid + p * 256;
      int jj = idx >> 6, kk = idx & 63;
      tile[jj][kk] = Wemb[(long)(j0 + jj) * 256 + k0 + kk];
    }
    __syncthreads();
#pragma unroll
    for (int p = 0; p < 16; ++p) {
      int idx = tid + p * 256;
      int kk = idx >> 6, jj = idx & 63;
      WembT[(long)(k0 + kk) * 512 + j0 + jj] = f2b(tile[jj][kk]);
    }
  } else if (bid < 6304) {
    // bfused[l][o] = dot(Wconv[l][o][:], bout[l][:]) + bconv[l][o]
    const int w = tid >> 6, lane = tid & 63;
    const int gi = (bid - 5920) * 4 + w;
    const int l = gi >> 9, o = gi & 511;
    float p = 0.f;
#pragma unroll
    for (int k = 0; k < 8; ++k)
      p += Wconv[(long)l * 262144 + (long)o * 512 + lane + 64 * k] *
           bout[l * 512 + lane + 64 * k];
#pragma unroll
    for (int msk = 1; msk <= 32; msk <<= 1) p += __shfl_xor(p, msk);
    if (lane == 0) bfused[gi] = p + bconv[l * 512 + o];
  } else {
    // bfq[o] = bin0[o] + dot(Win0[o][:], bemb[:])   (layer-0 bias fold)
    const int w = tid >> 6, lane = tid & 63;
    const int o = (bid - 6304) * 4 + w;
    float p = 0.f;
#pragma unroll
    for (int k = 0; k < 8; ++k)
      p += Win[(long)o * 512 + lane + 64 * k] * bemb[lane + 64 * k];
#pragma unroll
    for (int msk = 1; msk <= 32; msk <<= 1) p += __shfl_xor(p, msk);
    if (lane == 0) bfq[o] = p + bin0[o];
  }
}

// =========================================================================
// Attention over batch axis. Block (512 thr) per node n; cooperative
// coalesced load of q,k,v into LDS floats (stride 1540); wave = head.
// =========================================================================
__global__ __launch_bounds__(512) void attn_kernel(
    const ushort_t* __restrict__ qkv, ushort_t* __restrict__ outp)
{
  __shared__ float qs[8 * 1540];
  __shared__ float aw[8][64];
  const int tid = threadIdx.x;
  const int n = blockIdx.x;

  const ushort_t* src = qkv + (long)n * 1536;
#pragma unroll
  for (int p = 0; p < 3; ++p) {
    int c = tid + p * 512;
    int i = c / 192, off = (c % 192) * 8;
    ushortx8 u = *(const ushortx8*)(src + (long)i * 1024 * 1536 + off);
    float* d = &qs[i * 1540 + off];
#pragma unroll
    for (int r = 0; r < 8; ++r) d[r] = b2f(u[r]);
  }
  __syncthreads();

  const int h    = tid >> 6;
  const int lane = tid & 63;
  const int i = lane >> 3, j = lane & 7;
  float s = 0.f;
#pragma unroll 8
  for (int d = 0; d < 64; ++d)
    s += qs[i * 1540 + h * 64 + d] * qs[j * 1540 + 512 + h * 64 + d];
  s *= 0.125f;

  float m = s;
  m = fmaxf(m, __shfl_xor(m, 1));
  m = fmaxf(m, __shfl_xor(m, 2));
  m = fmaxf(m, __shfl_xor(m, 4));
  float e = __expf(s - m);
  float sum = e;
  sum += __shfl_xor(sum, 1);
  sum += __shfl_xor(sum, 2);
  sum += __shfl_xor(sum, 4);
  aw[h][lane] = e / sum;

  const long ob = (long)n * 512 + h * 64 + lane;
#pragma unroll
  for (int ii = 0; ii < 8; ++ii) {
    float acc = 0.f;
#pragma unroll
    for (int jj = 0; jj < 8; ++jj)
      acc += aw[h][ii * 8 + jj] * qs[jj * 1540 + 1024 + h * 64 + lane];
    outp[ob + (long)ii * 1024 * 512] = f2b(acc);
  }
}

// =========================================================================
// x_out(bf16) = LayerNorm(x + aggA+aggB). Wave per row (512).
// =========================================================================
__global__ __launch_bounds__(256) void ln_kernel(
    const ushort_t* __restrict__ xb,
    const ushort_t* __restrict__ aggA, const ushort_t* __restrict__ aggB,
    ushort_t* __restrict__ outB)
{
  const int w = threadIdx.x >> 6, lane = threadIdx.x & 63;
  const long base = ((long)blockIdx.x * 4 + w) * 512;
  float v[8];
  float s = 0.f;
#pragma unroll
  for (int k = 0; k < 8; ++k) {
    long idx = base + lane + 64 * k;
    v[k] = b2f(xb[idx]) + b2f(aggA[idx]) + b2f(aggB[idx]);
    s += v[k];
  }
#pragma unroll
  for (int msk = 1; msk <= 32; msk <<= 1) s += __shfl_xor(s, msk);
  float mean = s * (1.f / 512.f);
  float vv = 0.f;
#pragma unroll
  for (int k = 0; k < 8; ++k) { float d = v[k] - mean; vv += d * d; }
#pragma unroll
  for (int msk = 1; msk <= 32; msk <<= 1) vv += __shfl_xor(vv, msk);
  float inv = rsqrtf(vv * (1.f / 512.f) + 1e-5f);
#pragma unroll
  for (int k = 0; k < 8; ++k)
    outB[base + lane + 64 * k] = f2b((v[k] - mean) * inv);
}

// =========================================================================
// Final layer: LN -> out_x (fp32) + fused heads (mastery, diff, h1, h2)
// + per-block pool partials xp[2048][512] (for graph pooling).
// =========================================================================
__global__ __launch_bounds__(256) void final_ln_heads_kernel(
    const ushort_t* __restrict__ xb,
    const ushort_t* __restrict__ aggA, const ushort_t* __restrict__ aggB,
    float* __restrict__ out_x,
    const float* __restrict__ Wcls, const float* __restrict__ bcls,
    const float* __restrict__ Wdiff, const float* __restrict__ bdiff,
    const float* __restrict__ Wpre,
    float* __restrict__ mastery, float* __restrict__ diff,
    float* __restrict__ h1, float* __restrict__ h2,
    float* __restrict__ xp)
{
  __shared__ float sp4[4][512];
  const int w = threadIdx.x >> 6, lane = threadIdx.x & 63;
  const long row = (long)blockIdx.x * 4 + w;
  const long base = row * 512;
  float v[8];
  float s = 0.f;
#pragma unroll
  for (int k = 0; k < 8; ++k) {
    long idx = base + lane + 64 * k;
    v[k] = b2f(xb[idx]) + b2f(aggA[idx]) + b2f(aggB[idx]);
    s += v[k];
  }
#pragma unroll
  for (int msk = 1; msk <= 32; msk <<= 1) s += __shfl_xor(s, msk);
  float mean = s * (1.f / 512.f);
  float vv = 0.f;
#pragma unroll
  for (int k = 0; k < 8; ++k) { float d = v[k] - mean; vv += d * d; }
#pragma unroll
  for (int msk = 1; msk <= 32; msk <<= 1) vv += __shfl_xor(vv, msk);
  float inv = rsqrtf(vv * (1.f / 512.f) + 1e-5f);
#pragma unroll
  for (int k = 0; k < 8; ++k) {
    v[k] = (v[k] - mean) * inv;
    out_x[base + lane + 64 * k] = v[k];
    sp4[w][lane + 64 * k] = v[k];
  }
  __syncthreads();
  // block pool partial: sum of this block's 4 rows (all same batch: 256 blocks/batch)
  for (int t = threadIdx.x; t < 512; t += 256)
    xp[(long)blockIdx.x * 512 + t] =
        sp4[0][t] + sp4[1][t] + sp4[2][t] + sp4[3][t];
#pragma unroll
  for (int o = 0; o < 8; ++o) {
    const float* wp = (o == 0) ? Wcls
                    : (o <= 5) ? (Wdiff + (o - 1) * 512)
                    : (o == 6) ? Wpre : (Wpre + 512);
    float p = 0.f;
#pragma unroll
    for (int k = 0; k < 8; ++k) p += v[k] * wp[lane + 64 * k];
#pragma unroll
    for (int msk = 1; msk <= 32; msk <<= 1) p += __shfl_xor(p, msk);
    if (lane == 0) {
      if (o == 0)      mastery[row] = p + bcls[0];
      else if (o <= 5) diff[row * 5 + (o - 1)] = p + bdiff[o - 1];
      else if (o == 6) h1[row] = p;
      else             h2[row] = p;
    }
  }
}

// =========================================================================
// epilogue fused: [0,8192) prereq rows, [8192,8208) pool reduce xp -> xm.
// =========================================================================
__global__ __launch_bounds__(256) void epi_kernel(
    const float* __restrict__ h1, const float* __restrict__ h2,
    const float* __restrict__ bpre, float* __restrict__ outp,
    const float* __restrict__ xp, float* __restrict__ xm)
{
  const int bid = blockIdx.x;
  if (bid < 8192) {
    const int b = bid >> 10, i = bid & 1023;
    const float base = h1[b * 1024 + i] + bpre[0];
    const long ob = (long)b * (1024 * 1023) + (long)i * 1023;
#pragma unroll
    for (int r = 0; r < 4; ++r) {
      int j = r * 256 + threadIdx.x;
      if (j == i) continue;
      int pos = (j < i) ? j : j - 1;
      outp[ob + pos] = base + h2[b * 1024 + j];
    }
  } else {
    // xm[b][c] = sum over the 256 block-partials of batch b
    const int gi = (bid - 8192) * 256 + threadIdx.x;   // [0,4096)
    const int b = gi >> 9, c = gi & 511;
    const float* p = xp + (long)b * 256 * 512 + c;
    float s = 0.f;
    for (int q = 0; q < 256; ++q) s += p[q * 512];
    xm[b * 512 + c] = s;
  }
}

// graph[b,o] = (xm[b]/1024) . Wpool[o] + b_pool[o]
__global__ __launch_bounds__(256) void graph_kernel(
    const float* __restrict__ xm, const float* __restrict__ Wpool,
    const float* __restrict__ bpool, float* __restrict__ g)
{
  const int gi = blockIdx.x * 256 + threadIdx.x;
  const int b = gi >> 9, o = gi & 511;
  float s = 0.f;
  for (int hh = 0; hh < 512; ++hh) s += xm[b * 512 + hh] * Wpool[o * 512 + hh];
  g[gi] = s * (1.f / 1024.f) + bpool[o];
}

// =========================================================================
extern "C" void kernel_launch(void* const* d_in, const int* in_sizes, int n_in,
                              void* d_out, int out_size, void* d_ws, size_t ws_size,
                              hipStream_t stream)
{
  const float* CF    = (const float*)d_in[0];
  const float* ADJ   = (const float*)d_in[1];
  const float* Wemb  = (const float*)d_in[4];
  const float* bemb  = (const float*)d_in[5];
  const float* Win   = (const float*)d_in[6];
  const float* bin   = (const float*)d_in[7];
  const float* Wout  = (const float*)d_in[8];
  const float* bout  = (const float*)d_in[9];
  const float* Wconv = (const float*)d_in[10];
  const float* bconv = (const float*)d_in[11];
  const float* Wcls  = (const float*)d_in[12];
  const float* bcls  = (const float*)d_in[13];
  const float* Wdiff = (const float*)d_in[14];
  const float* bdiff = (const float*)d_in[15];
  const float* Wpre  = (const float*)d_in[16];
  const float* bpre  = (const float*)d_in[17];
  const float* Wpool = (const float*)d_in[18];
  const float* bpool = (const float*)d_in[19];

  // ---- workspace layout (ushort units). Total ~62 MB (< proven 84 MB). ----
  ushort_t* W = (ushort_t*)d_ws;
  ushort_t* xb   = W;                       // 4194304
  ushort_t* qkvb = W + 4194304;             // 12582912 (end 16777216)
  // aliases inside the qkv region (dead when their user runs):
  ushort_t* cT    = qkvb;                   // 4194304 (conv out, post-attn)
  ushort_t* aggA  = qkvb + 4194304;         // 4194304 (split-K part 0)
  ushort_t* aggB  = qkvb + 8388608;         // 4194304 (split-K part 1)
  // precompute scratch overlays aggA/B region (dead after setup GEMMs):
  ushort_t* WoT   = qkvb + 4194304;         // 786432
  ushort_t* Wembb = qkvb + 4980736;         // 131072
  ushort_t* Wcb   = qkvb + 5111808;         // 786432 (end 5898240)
  ushort_t* WembT = qkvb + 5898240;         // 131072 (end 6029312 < 8388608)
  // persistent:
  ushort_t* Winb = W + 16777216;            // 2359296
  ushort_t* Wfb  = W + 19136512;            // 786432 (fused Wconv@Wout)
  ushort_t* ADJb = W + 19922944;            // 8388608 (end 28311552)
  ushort_t* Wie  = W + 28311552;            // 393216 (Win0@Wemb, end 28704768)
  float* bfused = (float*)(W + 28704768);   // 1536
  float* bfq    = bfused + 1536;            // 1536
  float* h1     = bfq + 1536;               // 8192
  float* h2     = h1 + 8192;                // 8192
  float* xm     = h2 + 8192;                // 4096
  float* xp     = xm + 4096;                // 1048576 (pool partials)

  // ---- output layout (fp32 concat) + d_out-as-scratch aliases ----
  float* out_x       = (float*)d_out;       // 4194304
  float* out_mastery = out_x + 4194304;     // 8192
  float* out_diff    = out_mastery + 8192;  // 40960
  float* out_prereq  = out_diff + 40960;    // 8380416
  float* out_graph   = out_prereq + 8380416;// 4096
  // attn-out bf16 scratch in out_x region (dead before final LN writes it):
  ushort_t* aob = (ushort_t*)out_x;         // 4194304 ushorts

  dim3 blk(256);

  // ---- precompute: one dispatch ----
  prep_kernel<<<dim3(6688), blk, 0, stream>>>(
      Win, Winb, Wemb, Wembb, Wconv, Wcb, ADJ, ADJb,
      Wout, WoT, bout, bconv, bfused, WembT, bemb, bin, bfq);
  // Wie = Win0 @ Wemb  (1536 x 256 x 512): folds W_emb into layer-0 qkv
  gemm_bt<1, true, 1><<<dim3(2, 12, 1), blk, 0, stream>>>(
      Winb, WembT, nullptr, Wie, nullptr, nullptr, nullptr,
      1536, 256, 512, 0, 0, 0);
  // Wfused[l] = Wconv[l] @ Wout[l]  (batched z=3, 512x512x512)
  gemm_bt<1, true, 1><<<dim3(4, 4, 3), blk, 0, stream>>>(
      Wcb, WoT, nullptr, Wfb, nullptr, nullptr, nullptr,
      512, 512, 512, 262144, 262144, 262144);

  // x0 = CF @ Wemb^T + bemb  (8192 x 512 x 256, A fp32) — residual input
  gemm_bt<1, false, 1><<<dim3(4, 64, 1), blk, 0, stream>>>(
      CF, Wembb, bemb, xb, nullptr, nullptr, nullptr, 8192, 512, 256, 0, 0, 0);

  for (int l = 0; l < 3; ++l) {
    // qkv = x @ Win[l]^T + bin[l]
    if (l == 0) {
      // folded: qkv0 = CF @ Wie^T + bfq  (8192 x 1536 x 256, A fp32)
      gemm_bt<1, false, 1><<<dim3(12, 64, 1), blk, 0, stream>>>(
          CF, Wie, bfq, qkvb, nullptr, nullptr, nullptr,
          8192, 1536, 256, 0, 0, 0);
    } else {
      gemm_bt<1, true, 1><<<dim3(12, 64, 1), blk, 0, stream>>>(
          xb, Winb + (long)l * 786432, bin + l * 1536,
          qkvb, nullptr, nullptr, nullptr, 8192, 1536, 512, 0, 0, 0);
    }
    // attention over batch axis -> aob (out_x scratch)
    attn_kernel<<<dim3(1024), dim3(512), 0, stream>>>(qkvb, aob);
    // convT = (ao @ Wfused[l]^T + bfused[l]) transposed (qkv region dead)
    gemm_bt<2, true, 1><<<dim3(4, 64, 1), blk, 0, stream>>>(
        aob, Wfb + (long)l * 262144, bfused + l * 512,
        cT, nullptr, nullptr, nullptr, 8192, 512, 512, 0, 0, 0);
    // agg[b] = adj[b] @ conv[b]  (batched 1024x512x1024, split-K=2, bf16)
    gemm_bt<1, true, 2><<<dim3(4, 8, 16), blk, 0, stream>>>(
        ADJb, cT, nullptr, aggA, aggB, nullptr, nullptr,
        1024, 512, 1024, 1048576, 524288, 524288);
    // x = LN(x + aggA + aggB)
    if (l < 2)
      ln_kernel<<<dim3(2048), blk, 0, stream>>>(xb, aggA, aggB, xb);
    else
      final_ln_heads_kernel<<<dim3(2048), blk, 0, stream>>>(
          xb, aggA, aggB, out_x, Wcls, bcls, Wdiff, bdiff, Wpre,
          out_mastery, out_diff, h1, h2, xp);
  }

  epi_kernel<<<dim3(8208), blk, 0, stream>>>(h1, h2, bpre, out_prereq,
                                             xp, xm);
  graph_kernel<<<dim3(16), blk, 0, stream>>>(xm, Wpool, bpool, out_graph);
}

// Round 2
// 450.955 us; speedup vs baseline: 1.0180x; 1.0180x over previous
//
#include <hip/hip_runtime.h>
#include <hip/hip_bf16.h>

typedef unsigned short ushort_t;
typedef __attribute__((ext_vector_type(4))) float floatx4;
typedef __attribute__((ext_vector_type(8))) __bf16 bf16x8;
typedef __attribute__((ext_vector_type(4))) unsigned short ushortx4;
typedef __attribute__((ext_vector_type(8))) unsigned short ushortx8;

// ---------- bf16 helpers ----------
static __device__ __forceinline__ float b2f(ushort_t u) {
  union { unsigned int i; float f; } v; v.i = ((unsigned int)u) << 16; return v.f;
}
static __device__ __forceinline__ ushort_t f2b(float f) {
  unsigned int x = __float_as_uint(f);
  unsigned int r = (x + 0x7fffu + ((x >> 16) & 1u)) >> 16;
  return (ushort_t)r;
}
// async global->LDS, 16B per lane (dest = wave-uniform base + lane*16)
static __device__ __forceinline__ void glds16(const ushort_t* g, ushort_t* l) {
  __builtin_amdgcn_global_load_lds(
      (const __attribute__((address_space(1))) unsigned int*)g,
      (__attribute__((address_space(3))) unsigned int*)l, 16, 0, 0);
}

// =========================================================================
// GEMM: C[M,N] = A[M,K] @ B[N,K]^T (+bias[col]).  Single-plane bf16 MFMA.
// LDS bank-conflict fix: k-chunk XOR swizzle (slot c holds chunk c^(row&7)).
// XCD swizzle: lin = y*gridX+x; m = lin%gridY, n = lin/gridY.
// KS: split-K ways (1/4); blockIdx.z = z*KS+kq; partial kq -> Cout[kq].
// MODE 1: bf16 row-major (+z*cBatch)
// MODE 2: bf16 TRANSPOSED batched: [(b*N+col)*1024 + (m&1023)], b=m>>10
// MODE 3: split-N: cols [0,512)->C0 stride 512; [512,2048)->C1 stride 1536
// Block 256 = 4 waves; tile 128x128xBK64; wave 64x64 via 4x4 mfma 16x16x32.
// =========================================================================
template<int MODE, int KS>
__global__ __launch_bounds__(256, 3) void gemm_bt(
    const ushort_t* __restrict__ Ab, const ushort_t* __restrict__ Bm,
    const float* __restrict__ bias,
    ushort_t* __restrict__ C0, ushort_t* __restrict__ C1,
    ushort_t* __restrict__ C2, ushort_t* __restrict__ C3,
    int M, int N, int K, long aBatch, long bBatch, long cBatch)
{
  __shared__ __align__(16) ushort_t As[128 * 64];
  __shared__ __align__(16) ushort_t Bs[128 * 64];

  const int tid  = threadIdx.x;
  const int wid  = tid >> 6;
  const int lane = tid & 63;
  const int quad = lane >> 4;
  const int l16  = lane & 15;
  const int lin = blockIdx.y * gridDim.x + blockIdx.x;
  const int m0 = (lin % gridDim.y) * 128;
  const int n0 = (lin / gridDim.y) * 128;
  const int z  = (KS > 1) ? (int)(blockIdx.z / KS) : blockIdx.z;
  const int kq = (KS > 1) ? (int)(blockIdx.z % KS) : 0;
  const int kbeg = kq * (K / KS);
  const int kend = kbeg + (K / KS);
  ushort_t* outB = C0;
  if (KS >= 2 && kq == 1) outB = C1;
  if (KS >= 4 && kq == 2) outB = C2;
  if (KS >= 4 && kq == 3) outB = C3;

  Ab += (long)z * aBatch;
  Bm += (long)z * bBatch;

  const int wr = (wid >> 1) * 64;
  const int wc = (wid & 1) * 64;

  // staging: thread covers LDS slot (srow, tid&7); global source chunk is
  // XOR-swizzled: scj = (tid&7) ^ (srow&7)
  const int srow = tid >> 3;
  const int scj  = ((tid & 7) ^ (srow & 7)) * 8;
  const long abase = (long)(m0 + srow) * K + scj;
  const long bbase = (long)(n0 + srow) * K + scj;

  floatx4 acc[4][4];
#pragma unroll
  for (int i = 0; i < 4; ++i)
#pragma unroll
    for (int j = 0; j < 4; ++j) acc[i][j] = (floatx4){0.f, 0.f, 0.f, 0.f};

  const int rx = l16 & 7;   // row&7 for all fragment rows (wr,wc,i*16 mult 8)

  for (int k0 = kbeg; k0 < kend; k0 += 64) {
    __syncthreads();
#pragma unroll
    for (int p = 0; p < 4; ++p)
      glds16(Ab + abase + 32 * p * (long)K + k0, &As[tid * 8 + p * 2048]);
#pragma unroll
    for (int p = 0; p < 4; ++p)
      glds16(Bm + bbase + 32 * p * (long)K + k0, &Bs[tid * 8 + p * 2048]);
    __syncthreads();

#pragma unroll
    for (int kk = 0; kk < 2; ++kk) {
      bf16x8 a[4], b[4];
#pragma unroll
      for (int i = 0; i < 4; ++i)
        a[i] = *(const bf16x8*)(&As[(wr + i * 16 + l16) * 64 +
                                    (((kk * 4 + quad) ^ rx) << 3)]);
#pragma unroll
      for (int j = 0; j < 4; ++j)
        b[j] = *(const bf16x8*)(&Bs[(wc + j * 16 + l16) * 64 +
                                    (((kk * 4 + quad) ^ rx) << 3)]);
#pragma unroll
      for (int i = 0; i < 4; ++i)
#pragma unroll
        for (int j = 0; j < 4; ++j)
          acc[i][j] = __builtin_amdgcn_mfma_f32_16x16x32_bf16(a[i], b[j], acc[i][j], 0, 0, 0);
    }
  }

  // epilogue: lane = col l16; rows quad*4+r in each 16x16 sub-tile
#pragma unroll
  for (int j = 0; j < 4; ++j) {
    int col = n0 + wc + j * 16 + l16;
    float bv = (bias != nullptr) ? bias[col] : 0.f;
#pragma unroll
    for (int i = 0; i < 4; ++i) {
      int mbase = m0 + wr + i * 16 + quad * 4;
      if constexpr (MODE == 1) {
#pragma unroll
        for (int r = 0; r < 4; ++r)
          outB[(long)z * cBatch + (long)(mbase + r) * N + col] = f2b(acc[i][j][r] + bv);
      } else if constexpr (MODE == 2) {
        int b = mbase >> 10, jrow = mbase & 1023;
        ushortx4 pk;
#pragma unroll
        for (int r = 0; r < 4; ++r) pk[r] = f2b(acc[i][j][r] + bv);
        *(ushortx4*)(outB + ((long)b * N + col) * 1024 + jrow) = pk;
      } else {
        // MODE 3: fused x0|qkv0 split-N (n-tiles are 128-wide, so a whole
        // block is on one side of col 512)
        ushort_t* o = (n0 < 512) ? C0 : C1;
        const int cw = (n0 < 512) ? 512 : 1536;
        const int cc = (n0 < 512) ? col : col - 512;
#pragma unroll
        for (int r = 0; r < 4; ++r)
          o[(long)(mbase + r) * cw + cc] = f2b(acc[i][j][r] + bv);
      }
    }
  }
}

// =========================================================================
// prep (one dispatch): fp32->bf16 conversions (Win, Wemb->Wq0 head, Wconv,
// ADJ, CF), Wout transpose, Wemb transpose, bfused, folded layer-0 bias.
// blocks: [0,1152) Win | [1152,1216) Wemb->Wq0 | [1216,1600) Wconv |
// [1600,5696) ADJ | [5696,6720) CF | [6720,6912) WoutT | [6912,6944) WembT |
// [6944,7328) bfuse | [7328,7712) bfq->bcat+512 | [7712,7714) bemb->bcat
// =========================================================================
__global__ __launch_bounds__(256) void prep_kernel(
    const float* __restrict__ Win,  ushort_t* __restrict__ Winb,
    const float* __restrict__ Wemb, ushort_t* __restrict__ Wq0,
    const float* __restrict__ Wconv, ushort_t* __restrict__ Wcb,
    const float* __restrict__ ADJ,  ushort_t* __restrict__ ADJb,
    const float* __restrict__ CF,   ushort_t* __restrict__ CFb,
    const float* __restrict__ Wout, ushort_t* __restrict__ WoT,
    const float* __restrict__ bout, const float* __restrict__ bconv,
    float* __restrict__ bfused,
    ushort_t* __restrict__ WembT,
    const float* __restrict__ bemb, const float* __restrict__ bin0,
    float* __restrict__ bcat)
{
  __shared__ float tile[64][65];
  const int bid = blockIdx.x, tid = threadIdx.x;
  if (bid < 6720) {
    const float* src; ushort_t* dst; long i;
    if (bid < 1152)      { src = Win;   dst = Winb; i = (long)bid * 256 + tid; }
    else if (bid < 1216) { src = Wemb;  dst = Wq0;  i = (long)(bid - 1152) * 256 + tid; }
    else if (bid < 1600) { src = Wconv; dst = Wcb;  i = (long)(bid - 1216) * 256 + tid; }
    else if (bid < 5696) { src = ADJ;   dst = ADJb; i = (long)(bid - 1600) * 256 + tid; }
    else                 { src = CF;    dst = CFb;  i = (long)(bid - 5696) * 256 + tid; }
    floatx4 a = ((const floatx4*)src)[2 * i];
    floatx4 b = ((const floatx4*)src)[2 * i + 1];
    ushortx4 ha, hb;
#pragma unroll
    for (int r = 0; r < 4; ++r) { ha[r] = f2b(a[r]); hb[r] = f2b(b[r]); }
    ((ushortx4*)dst)[2 * i] = ha; ((ushortx4*)dst)[2 * i + 1] = hb;
  } else if (bid < 6912) {
    // transpose+cvt: T[l][k][j] = bf16(Wout[l][j][k])
    const int t = bid - 6720;
    const int z = t >> 6, k0 = ((t >> 3) & 7) * 64, j0 = (t & 7) * 64;
    const long base = (long)z * 262144;
#pragma unroll
    for (int p = 0; p < 16; ++p) {
      int idx = tid + p * 256;
      int jj = idx >> 6, kk = idx & 63;
      tile[jj][kk] = Wout[base + (long)(j0 + jj) * 512 + k0 + kk];
    }
    __syncthreads();
#pragma unroll
    for (int p = 0; p < 16; ++p) {
      int idx = tid + p * 256;
      int kk = idx >> 6, jj = idx & 63;
      WoT[base + (long)(k0 + kk) * 512 + j0 + jj] = f2b(tile[jj][kk]);
    }
  } else if (bid < 6944) {
    // WembT[c][h] = bf16(Wemb[h][c])  (Wemb is [512][256])
    const int t = bid - 6912;
    const int j0 = (t >> 2) * 64, k0 = (t & 3) * 64;
#pragma unroll
    for (int p = 0; p < 16; ++p) {
      int idx = tid + p * 256;
      int jj = idx >> 6, kk = idx & 63;
      tile[jj][kk] = Wemb[(long)(j0 + jj) * 256 + k0 + kk];
    }
    __syncthreads();
#pragma unroll
    for (int p = 0; p < 16; ++p) {
      int idx = tid + p * 256;
      int kk = idx >> 6, jj = idx & 63;
      WembT[(long)(k0 + kk) * 512 + j0 + jj] = f2b(tile[jj][kk]);
    }
  } else if (bid < 7328) {
    // bfused[l][o] = dot(Wconv[l][o][:], bout[l][:]) + bconv[l][o]
    const int w = tid >> 6, lane = tid & 63;
    const int gi = (bid - 6944) * 4 + w;
    const int l = gi >> 9, o = gi & 511;
    float p = 0.f;
#pragma unroll
    for (int k = 0; k < 8; ++k)
      p += Wconv[(long)l * 262144 + (long)o * 512 + lane + 64 * k] *
           bout[l * 512 + lane + 64 * k];
#pragma unroll
    for (int msk = 1; msk <= 32; msk <<= 1) p += __shfl_xor(p, msk);
    if (lane == 0) bfused[gi] = p + bconv[l * 512 + o];
  } else if (bid < 7712) {
    // bcat[512+o] = bin0[o] + dot(Win0[o][:], bemb[:])  (layer-0 bias fold)
    const int w = tid >> 6, lane = tid & 63;
    const int o = (bid - 7328) * 4 + w;
    float p = 0.f;
#pragma unroll
    for (int k = 0; k < 8; ++k)
      p += Win[(long)o * 512 + lane + 64 * k] * bemb[lane + 64 * k];
#pragma unroll
    for (int msk = 1; msk <= 32; msk <<= 1) p += __shfl_xor(p, msk);
    if (lane == 0) bcat[512 + o] = p + bin0[o];
  } else {
    // bcat[0:512] = bemb
    int idx = (bid - 7712) * 256 + tid;
    bcat[idx] = bemb[idx];
  }
}

// =========================================================================
// Attention over batch axis. Block (512 thr) per node n; qkv staged in LDS
// as bf16 (source already bf16 -> lossless), ~27 KB -> 4 blocks/CU, grid
// 1024 fully resident. Wave = head. Stride 1544 puts the 8 Q/K row bases
// on 8 distinct banks.
// =========================================================================
__global__ __launch_bounds__(512, 8) void attn_kernel(
    const ushort_t* __restrict__ qkv, ushort_t* __restrict__ outp)
{
  __shared__ ushort_t qs[8 * 1544];
  __shared__ float aw[8][64];
  const int tid = threadIdx.x;
  const int n = blockIdx.x;

  const ushort_t* src = qkv + (long)n * 1536;
#pragma unroll
  for (int p = 0; p < 3; ++p) {
    int c = tid + p * 512;
    int i = c / 192, off = (c % 192) * 8;
    *(ushortx8*)(&qs[i * 1544 + off]) =
        *(const ushortx8*)(src + (long)i * 1024 * 1536 + off);
  }
  __syncthreads();

  const int h    = tid >> 6;
  const int lane = tid & 63;
  const int i = lane >> 3, j = lane & 7;
  const ushort_t* qrow = &qs[i * 1544 + h * 64];
  const ushort_t* krow = &qs[j * 1544 + 512 + h * 64];
  float s = 0.f;
#pragma unroll
  for (int c8 = 0; c8 < 8; ++c8) {
    ushortx8 qa = *(const ushortx8*)(qrow + c8 * 8);
    ushortx8 ka = *(const ushortx8*)(krow + c8 * 8);
#pragma unroll
    for (int r = 0; r < 8; ++r) s += b2f(qa[r]) * b2f(ka[r]);
  }
  s *= 0.125f;

  float m = s;
  m = fmaxf(m, __shfl_xor(m, 1));
  m = fmaxf(m, __shfl_xor(m, 2));
  m = fmaxf(m, __shfl_xor(m, 4));
  float e = __expf(s - m);
  float sum = e;
  sum += __shfl_xor(sum, 1);
  sum += __shfl_xor(sum, 2);
  sum += __shfl_xor(sum, 4);
  aw[h][lane] = e / sum;   // written+read by the same wave; no barrier needed

  // PV: hoist v into regs (channel = h*64 + lane)
  float vv[8];
#pragma unroll
  for (int jj = 0; jj < 8; ++jj)
    vv[jj] = b2f(qs[jj * 1544 + 1024 + h * 64 + lane]);
  const long ob = (long)n * 512 + h * 64 + lane;
#pragma unroll
  for (int ii = 0; ii < 8; ++ii) {
    float acc = 0.f;
#pragma unroll
    for (int jj = 0; jj < 8; ++jj) acc += aw[h][ii * 8 + jj] * vv[jj];
    outp[ob + (long)ii * 1024 * 512] = f2b(acc);
  }
}

// =========================================================================
// x_out(bf16) = LayerNorm(x + aggA+aggB+aggC+aggD). Wave per row (512).
// =========================================================================
__global__ __launch_bounds__(256) void ln_kernel(
    const ushort_t* __restrict__ xb,
    const ushort_t* __restrict__ aggA, const ushort_t* __restrict__ aggB,
    const ushort_t* __restrict__ aggC, const ushort_t* __restrict__ aggD,
    ushort_t* __restrict__ outB)
{
  const int w = threadIdx.x >> 6, lane = threadIdx.x & 63;
  const long base = ((long)blockIdx.x * 4 + w) * 512;
  float v[8];
  float s = 0.f;
#pragma unroll
  for (int k = 0; k < 8; ++k) {
    long idx = base + lane + 64 * k;
    v[k] = b2f(xb[idx]) + b2f(aggA[idx]) + b2f(aggB[idx]) +
           b2f(aggC[idx]) + b2f(aggD[idx]);
    s += v[k];
  }
#pragma unroll
  for (int msk = 1; msk <= 32; msk <<= 1) s += __shfl_xor(s, msk);
  float mean = s * (1.f / 512.f);
  float vv = 0.f;
#pragma unroll
  for (int k = 0; k < 8; ++k) { float d = v[k] - mean; vv += d * d; }
#pragma unroll
  for (int msk = 1; msk <= 32; msk <<= 1) vv += __shfl_xor(vv, msk);
  float inv = rsqrtf(vv * (1.f / 512.f) + 1e-5f);
#pragma unroll
  for (int k = 0; k < 8; ++k)
    outB[base + lane + 64 * k] = f2b((v[k] - mean) * inv);
}

// =========================================================================
// Final layer: LN -> out_x (fp32) + fused heads (mastery, diff, h1, h2)
// + per-block pool partials xp[2048][512] (for graph pooling).
// =========================================================================
__global__ __launch_bounds__(256) void final_ln_heads_kernel(
    const ushort_t* __restrict__ xb,
    const ushort_t* __restrict__ aggA, const ushort_t* __restrict__ aggB,
    const ushort_t* __restrict__ aggC, const ushort_t* __restrict__ aggD,
    float* __restrict__ out_x,
    const float* __restrict__ Wcls, const float* __restrict__ bcls,
    const float* __restrict__ Wdiff, const float* __restrict__ bdiff,
    const float* __restrict__ Wpre,
    float* __restrict__ mastery, float* __restrict__ diff,
    float* __restrict__ h1, float* __restrict__ h2,
    float* __restrict__ xp)
{
  __shared__ float sp4[4][512];
  const int w = threadIdx.x >> 6, lane = threadIdx.x & 63;
  const long row = (long)blockIdx.x * 4 + w;
  const long base = row * 512;
  float v[8];
  float s = 0.f;
#pragma unroll
  for (int k = 0; k < 8; ++k) {
    long idx = base + lane + 64 * k;
    v[k] = b2f(xb[idx]) + b2f(aggA[idx]) + b2f(aggB[idx]) +
           b2f(aggC[idx]) + b2f(aggD[idx]);
    s += v[k];
  }
#pragma unroll
  for (int msk = 1; msk <= 32; msk <<= 1) s += __shfl_xor(s, msk);
  float mean = s * (1.f / 512.f);
  float vv = 0.f;
#pragma unroll
  for (int k = 0; k < 8; ++k) { float d = v[k] - mean; vv += d * d; }
#pragma unroll
  for (int msk = 1; msk <= 32; msk <<= 1) vv += __shfl_xor(vv, msk);
  float inv = rsqrtf(vv * (1.f / 512.f) + 1e-5f);
#pragma unroll
  for (int k = 0; k < 8; ++k) {
    v[k] = (v[k] - mean) * inv;
    out_x[base + lane + 64 * k] = v[k];
    sp4[w][lane + 64 * k] = v[k];
  }
  __syncthreads();
  // block pool partial: sum of this block's 4 rows (256 blocks/batch)
  for (int t = threadIdx.x; t < 512; t += 256)
    xp[(long)blockIdx.x * 512 + t] =
        sp4[0][t] + sp4[1][t] + sp4[2][t] + sp4[3][t];
#pragma unroll
  for (int o = 0; o < 8; ++o) {
    const float* wp = (o == 0) ? Wcls
                    : (o <= 5) ? (Wdiff + (o - 1) * 512)
                    : (o == 6) ? Wpre : (Wpre + 512);
    float p = 0.f;
#pragma unroll
    for (int k = 0; k < 8; ++k) p += v[k] * wp[lane + 64 * k];
#pragma unroll
    for (int msk = 1; msk <= 32; msk <<= 1) p += __shfl_xor(p, msk);
    if (lane == 0) {
      if (o == 0)      mastery[row] = p + bcls[0];
      else if (o <= 5) diff[row * 5 + (o - 1)] = p + bdiff[o - 1];
      else if (o == 6) h1[row] = p;
      else             h2[row] = p;
    }
  }
}

// =========================================================================
// epilogue fused: [0,8192) prereq rows, [8192,8208) pool reduce xp -> xm.
// =========================================================================
__global__ __launch_bounds__(256) void epi_kernel(
    const float* __restrict__ h1, const float* __restrict__ h2,
    const float* __restrict__ bpre, float* __restrict__ outp,
    const float* __restrict__ xp, float* __restrict__ xm)
{
  const int bid = blockIdx.x;
  if (bid < 8192) {
    const int b = bid >> 10, i = bid & 1023;
    const float base = h1[b * 1024 + i] + bpre[0];
    const long ob = (long)b * (1024 * 1023) + (long)i * 1023;
#pragma unroll
    for (int r = 0; r < 4; ++r) {
      int j = r * 256 + threadIdx.x;
      if (j == i) continue;
      int pos = (j < i) ? j : j - 1;
      outp[ob + pos] = base + h2[b * 1024 + j];
    }
  } else {
    // xm[b][c] = sum over the 256 block-partials of batch b
    const int gi = (bid - 8192) * 256 + threadIdx.x;   // [0,4096)
    const int b = gi >> 9, c = gi & 511;
    const float* p = xp + (long)b * 256 * 512 + c;
    float s = 0.f;
    for (int q = 0; q < 256; ++q) s += p[q * 512];
    xm[b * 512 + c] = s;
  }
}

// graph[b,o] = (xm[b]/1024) . Wpool[o] + b_pool[o]
__global__ __launch_bounds__(256) void graph_kernel(
    const float* __restrict__ xm, const float* __restrict__ Wpool,
    const float* __restrict__ bpool, float* __restrict__ g)
{
  const int gi = blockIdx.x * 256 + threadIdx.x;
  const int b = gi >> 9, o = gi & 511;
  float s = 0.f;
  for (int hh = 0; hh < 512; ++hh) s += xm[b * 512 + hh] * Wpool[o * 512 + hh];
  g[gi] = s * (1.f / 1024.f) + bpool[o];
}

// =========================================================================
extern "C" void kernel_launch(void* const* d_in, const int* in_sizes, int n_in,
                              void* d_out, int out_size, void* d_ws, size_t ws_size,
                              hipStream_t stream)
{
  const float* CF    = (const float*)d_in[0];
  const float* ADJ   = (const float*)d_in[1];
  const float* Wemb  = (const float*)d_in[4];
  const float* bemb  = (const float*)d_in[5];
  const float* Win   = (const float*)d_in[6];
  const float* bin   = (const float*)d_in[7];
  const float* Wout  = (const float*)d_in[8];
  const float* bout  = (const float*)d_in[9];
  const float* Wconv = (const float*)d_in[10];
  const float* bconv = (const float*)d_in[11];
  const float* Wcls  = (const float*)d_in[12];
  const float* bcls  = (const float*)d_in[13];
  const float* Wdiff = (const float*)d_in[14];
  const float* bdiff = (const float*)d_in[15];
  const float* Wpre  = (const float*)d_in[16];
  const float* bpre  = (const float*)d_in[17];
  const float* Wpool = (const float*)d_in[18];
  const float* bpool = (const float*)d_in[19];

  // ---- workspace layout (ushort units). Total ~70.4 MB (< proven 84 MB). ----
  ushort_t* W = (ushort_t*)d_ws;
  ushort_t* xb   = W;                       // 4194304
  ushort_t* qkvb = W + 4194304;             // 12582912 (end 16777216)
  // aliases inside the qkv region (dead when their user runs):
  ushort_t* cT    = qkvb;                   // 4194304 (conv out, post-attn)
  ushort_t* aggA  = qkvb + 4194304;         // 4194304 (split-K part 0)
  ushort_t* aggB  = qkvb + 8388608;         // 4194304 (split-K part 1)
  // precompute scratch overlays aggA/B region (dead before qkv0 GEMM):
  ushort_t* WoT   = qkvb + 4194304;         // 786432
  ushort_t* Wcb   = qkvb + 4980736;         // 786432
  ushort_t* WembT = qkvb + 5767168;         // 131072 (end 5898240 < 8388608)
  // persistent:
  ushort_t* Winb = W + 16777216;            // 2359296
  ushort_t* Wfb  = W + 19136512;            // 786432 (fused Wconv@Wout)
  ushort_t* ADJb = W + 19922944;            // 8388608 (end 28311552)
  ushort_t* CFb  = W + 28311552;            // 4194304 (end 32505856)
  ushort_t* Wq0  = W + 32505856;            // 524288 (rows 0-511 Wemb, 512-2047 Win0@Wemb)
  float* bfused = (float*)(W + 33030144);   // 1536
  float* bcat   = bfused + 1536;            // 2048 (bemb ++ folded qkv0 bias)
  float* h1     = bcat + 2048;              // 8192
  float* h2     = h1 + 8192;                // 8192
  float* xm     = h2 + 8192;                // 4096
  float* xp     = xm + 4096;                // 1048576 (pool partials)

  // ---- output layout (fp32 concat) + d_out-as-scratch aliases ----
  float* out_x       = (float*)d_out;       // 4194304
  float* out_mastery = out_x + 4194304;     // 8192
  float* out_diff    = out_mastery + 8192;  // 40960
  float* out_prereq  = out_diff + 40960;    // 8380416
  float* out_graph   = out_prereq + 8380416;// 4096
  // attn-out bf16 scratch in out_x region (dead before final LN writes it):
  ushort_t* aob = (ushort_t*)out_x;         // 4194304 ushorts
  // split-K parts 2,3 live in out_prereq region (written only by epi at end):
  ushort_t* aggC = (ushort_t*)out_prereq;            // 4194304
  ushort_t* aggD = (ushort_t*)out_prereq + 4194304;  // 4194304 (16.8M<33.5M ok)

  dim3 blk(256);

  // ---- precompute: one dispatch ----
  prep_kernel<<<dim3(7714), blk, 0, stream>>>(
      Win, Winb, Wemb, Wq0, Wconv, Wcb, ADJ, ADJb, CF, CFb,
      Wout, WoT, bout, bconv, bfused, WembT, bemb, bin, bcat);
  // Wq0 tail = Win0 @ Wemb (1536 x 256 x 512): folds W_emb into layer-0 qkv
  gemm_bt<1, 1><<<dim3(2, 12, 1), blk, 0, stream>>>(
      Winb, WembT, nullptr, Wq0 + 512 * 256, nullptr, nullptr, nullptr,
      1536, 256, 512, 0, 0, 0);
  // Wfused[l] = Wconv[l] @ Wout[l]  (batched z=3, 512x512x512)
  gemm_bt<1, 1><<<dim3(4, 4, 3), blk, 0, stream>>>(
      Wcb, WoT, nullptr, Wfb, nullptr, nullptr, nullptr,
      512, 512, 512, 262144, 262144, 262144);

  for (int l = 0; l < 3; ++l) {
    // qkv = x @ Win[l]^T + bin[l]
    if (l == 0) {
      // fused x0|qkv0: [xb | qkvb] = CFb @ Wq0^T + bcat  (8192 x 2048 x 256)
      gemm_bt<3, 1><<<dim3(16, 64, 1), blk, 0, stream>>>(
          CFb, Wq0, bcat, xb, qkvb, nullptr, nullptr,
          8192, 2048, 256, 0, 0, 0);
    } else {
      gemm_bt<1, 1><<<dim3(12, 64, 1), blk, 0, stream>>>(
          xb, Winb + (long)l * 786432, bin + l * 1536,
          qkvb, nullptr, nullptr, nullptr, 8192, 1536, 512, 0, 0, 0);
    }
    // attention over batch axis -> aob (out_x scratch)
    attn_kernel<<<dim3(1024), dim3(512), 0, stream>>>(qkvb, aob);
    // convT = (ao @ Wfused[l]^T + bfused[l]) transposed (qkv region dead)
    gemm_bt<2, 1><<<dim3(4, 64, 1), blk, 0, stream>>>(
        aob, Wfb + (long)l * 262144, bfused + l * 512,
        cT, nullptr, nullptr, nullptr, 8192, 512, 512, 0, 0, 0);
    // agg[b] = adj[b] @ conv[b]  (batched 1024x512x1024, split-K=4, bf16)
    gemm_bt<1, 4><<<dim3(4, 8, 32), blk, 0, stream>>>(
        ADJb, cT, nullptr, aggA, aggB, aggC, aggD,
        1024, 512, 1024, 1048576, 524288, 524288);
    // x = LN(x + aggA + aggB + aggC + aggD)
    if (l < 2)
      ln_kernel<<<dim3(2048), blk, 0, stream>>>(xb, aggA, aggB, aggC, aggD, xb);
    else
      final_ln_heads_kernel<<<dim3(2048), blk, 0, stream>>>(
          xb, aggA, aggB, aggC, aggD, out_x, Wcls, bcls, Wdiff, bdiff, Wpre,
          out_mastery, out_diff, h1, h2, xp);
  }

  epi_kernel<<<dim3(8208), blk, 0, stream>>>(h1, h2, bpre, out_prereq,
                                             xp, xm);
  graph_kernel<<<dim3(16), blk, 0, stream>>>(xm, Wpool, bpool, out_graph);
}

// Round 3
// 432.882 us; speedup vs baseline: 1.0605x; 1.0417x over previous
//
#include <hip/hip_runtime.h>
#include <hip/hip_bf16.h>

typedef unsigned short ushort_t;
typedef __attribute__((ext_vector_type(4))) float floatx4;
typedef __attribute__((ext_vector_type(8))) __bf16 bf16x8;
typedef __attribute__((ext_vector_type(4))) unsigned short ushortx4;
typedef __attribute__((ext_vector_type(8))) unsigned short ushortx8;

// ---------- bf16 helpers ----------
static __device__ __forceinline__ float b2f(ushort_t u) {
  union { unsigned int i; float f; } v; v.i = ((unsigned int)u) << 16; return v.f;
}
static __device__ __forceinline__ ushort_t f2b(float f) {
  unsigned int x = __float_as_uint(f);
  unsigned int r = (x + 0x7fffu + ((x >> 16) & 1u)) >> 16;
  return (ushort_t)r;
}
// async global->LDS, 16B per lane (dest = wave-uniform base + lane*16)
static __device__ __forceinline__ void glds16(const ushort_t* g, ushort_t* l) {
  __builtin_amdgcn_global_load_lds(
      (const __attribute__((address_space(1))) unsigned int*)g,
      (__attribute__((address_space(3))) unsigned int*)l, 16, 0, 0);
}

// =========================================================================
// GEMM core: C[m0:+128, n0:+128] = A[M,K] @ B[N,K]^T (+bias[col]).
// bf16 MFMA, tile 128x128xBK64, 4 waves, wave 64x64 via 4x4 mfma 16x16x32.
// LDS bank-conflict fix: k-chunk XOR swizzle (slot c holds chunk c^(row&7)).
// MODE 1: bf16 row-major [M,N] (caller folds batch offset into outB)
// MODE 2: bf16 TRANSPOSED batched: [(b*N+col)*1024 + (m&1023)], b=m>>10
// MODE 3: split-N: cols [0,512)->outB stride 512; [512,2048)->C1 stride 1536
// =========================================================================
template<int MODE>
static __device__ __forceinline__ void gemm_core(
    const ushort_t* __restrict__ Ab, const ushort_t* __restrict__ Bm,
    const float* __restrict__ bias,
    ushort_t* __restrict__ outB, ushort_t* __restrict__ C1,
    int N, int K, int m0, int n0, int kbeg, int kend,
    ushort_t* As, ushort_t* Bs)
{
  const int tid  = threadIdx.x;
  const int wid  = tid >> 6;
  const int lane = tid & 63;
  const int quad = lane >> 4;
  const int l16  = lane & 15;

  const int wr = (wid >> 1) * 64;
  const int wc = (wid & 1) * 64;

  // staging: thread covers LDS slot (srow, tid&7); global source chunk is
  // XOR-swizzled: scj = (tid&7) ^ (srow&7)
  const int srow = tid >> 3;
  const int scj  = ((tid & 7) ^ (srow & 7)) * 8;
  const long abase = (long)(m0 + srow) * K + scj;
  const long bbase = (long)(n0 + srow) * K + scj;

  floatx4 acc[4][4];
#pragma unroll
  for (int i = 0; i < 4; ++i)
#pragma unroll
    for (int j = 0; j < 4; ++j) acc[i][j] = (floatx4){0.f, 0.f, 0.f, 0.f};

  const int rx = l16 & 7;   // row&7 for all fragment rows (wr,wc,i*16 mult 8)

  for (int k0 = kbeg; k0 < kend; k0 += 64) {
    __syncthreads();
#pragma unroll
    for (int p = 0; p < 4; ++p)
      glds16(Ab + abase + 32 * p * (long)K + k0, &As[tid * 8 + p * 2048]);
#pragma unroll
    for (int p = 0; p < 4; ++p)
      glds16(Bm + bbase + 32 * p * (long)K + k0, &Bs[tid * 8 + p * 2048]);
    __syncthreads();

#pragma unroll
    for (int kk = 0; kk < 2; ++kk) {
      bf16x8 a[4], b[4];
#pragma unroll
      for (int i = 0; i < 4; ++i)
        a[i] = *(const bf16x8*)(&As[(wr + i * 16 + l16) * 64 +
                                    (((kk * 4 + quad) ^ rx) << 3)]);
#pragma unroll
      for (int j = 0; j < 4; ++j)
        b[j] = *(const bf16x8*)(&Bs[(wc + j * 16 + l16) * 64 +
                                    (((kk * 4 + quad) ^ rx) << 3)]);
#pragma unroll
      for (int i = 0; i < 4; ++i)
#pragma unroll
        for (int j = 0; j < 4; ++j)
          acc[i][j] = __builtin_amdgcn_mfma_f32_16x16x32_bf16(a[i], b[j], acc[i][j], 0, 0, 0);
    }
  }

  // epilogue: lane = col l16; rows quad*4+r in each 16x16 sub-tile
#pragma unroll
  for (int j = 0; j < 4; ++j) {
    int col = n0 + wc + j * 16 + l16;
    float bv = (bias != nullptr) ? bias[col] : 0.f;
#pragma unroll
    for (int i = 0; i < 4; ++i) {
      int mbase = m0 + wr + i * 16 + quad * 4;
      if constexpr (MODE == 1) {
#pragma unroll
        for (int r = 0; r < 4; ++r)
          outB[(long)(mbase + r) * N + col] = f2b(acc[i][j][r] + bv);
      } else if constexpr (MODE == 2) {
        int b = mbase >> 10, jrow = mbase & 1023;
        ushortx4 pk;
#pragma unroll
        for (int r = 0; r < 4; ++r) pk[r] = f2b(acc[i][j][r] + bv);
        *(ushortx4*)(outB + ((long)b * N + col) * 1024 + jrow) = pk;
      } else {
        // MODE 3: fused x0|qkv0 split-N (n-tiles are 128-wide, so a whole
        // block is on one side of col 512)
        ushort_t* o = (n0 < 512) ? outB : C1;
        const int cw = (n0 < 512) ? 512 : 1536;
        const int cc = (n0 < 512) ? col : col - 512;
#pragma unroll
        for (int r = 0; r < 4; ++r)
          o[(long)(mbase + r) * cw + cc] = f2b(acc[i][j][r] + bv);
      }
    }
  }
}

// generic dispatcher: XCD swizzle lin = y*gridX+x; m = lin%gridY, n = lin/gridY
// KS: split-K ways; blockIdx.z = z*KS+kq; partial kq -> C{kq}.
template<int MODE, int KS>
__global__ __launch_bounds__(256, 3) void gemm_bt(
    const ushort_t* __restrict__ Ab, const ushort_t* __restrict__ Bm,
    const float* __restrict__ bias,
    ushort_t* __restrict__ C0, ushort_t* __restrict__ C1,
    int N, int K, long aBatch, long bBatch, long cBatch)
{
  __shared__ __align__(16) ushort_t As[128 * 64];
  __shared__ __align__(16) ushort_t Bs[128 * 64];
  const int lin = blockIdx.y * gridDim.x + blockIdx.x;
  const int m0 = (lin % gridDim.y) * 128;
  const int n0 = (lin / gridDim.y) * 128;
  const int z  = (KS > 1) ? (int)(blockIdx.z / KS) : blockIdx.z;
  const int kq = (KS > 1) ? (int)(blockIdx.z % KS) : 0;
  const int kbeg = kq * (K / KS);
  const int kend = kbeg + (K / KS);
  ushort_t* outB = (KS >= 2 && kq == 1) ? C1 : C0;
  gemm_core<MODE>(Ab + (long)z * aBatch, Bm + (long)z * bBatch, bias,
                  outB + ((MODE == 1) ? (long)z * cBatch : 0), C1,
                  N, K, m0, n0, kbeg, kend, As, Bs);
}

// setup GEMMs merged: z<3 -> Wfused[z] = Wconv[z] @ Wout[z] (512x512x512);
// z==3 -> Wq0 tail = Win0 @ Wemb (1536x256x512). Grid (24,1,4).
__global__ __launch_bounds__(256, 3) void setup_gemm(
    const ushort_t* __restrict__ Wcb, const ushort_t* __restrict__ WoT,
    ushort_t* __restrict__ Wfb,
    const ushort_t* __restrict__ Winb, const ushort_t* __restrict__ WembT,
    ushort_t* __restrict__ Wq0t)
{
  __shared__ __align__(16) ushort_t As[128 * 64];
  __shared__ __align__(16) ushort_t Bs[128 * 64];
  const int lin = blockIdx.x;
  const int z = blockIdx.z;
  if (z < 3) {
    if (lin >= 16) return;   // block-uniform exit, before any barrier
    const long off = (long)z * 262144;
    gemm_core<1>(Wcb + off, WoT + off, nullptr, Wfb + off, nullptr,
                 512, 512, (lin & 3) * 128, (lin >> 2) * 128, 0, 512, As, Bs);
  } else {
    gemm_core<1>(Winb, WembT, nullptr, Wq0t, nullptr,
                 256, 512, (lin % 12) * 128, (lin / 12) * 128, 0, 512, As, Bs);
  }
}

// =========================================================================
// prep (one dispatch): fp32->bf16 conversions (Win, Wemb->Wq0 head, Wconv,
// ADJ, CF), Wout transpose, Wemb transpose, bfused, folded layer-0 bias.
// blocks: [0,1152) Win | [1152,1216) Wemb->Wq0 | [1216,1600) Wconv |
// [1600,5696) ADJ | [5696,6720) CF | [6720,6912) WoutT | [6912,6944) WembT |
// [6944,7328) bfuse | [7328,7712) bfq->bcat+512 | [7712,7714) bemb->bcat
// =========================================================================
__global__ __launch_bounds__(256) void prep_kernel(
    const float* __restrict__ Win,  ushort_t* __restrict__ Winb,
    const float* __restrict__ Wemb, ushort_t* __restrict__ Wq0,
    const float* __restrict__ Wconv, ushort_t* __restrict__ Wcb,
    const float* __restrict__ ADJ,  ushort_t* __restrict__ ADJb,
    const float* __restrict__ CF,   ushort_t* __restrict__ CFb,
    const float* __restrict__ Wout, ushort_t* __restrict__ WoT,
    const float* __restrict__ bout, const float* __restrict__ bconv,
    float* __restrict__ bfused,
    ushort_t* __restrict__ WembT,
    const float* __restrict__ bemb, const float* __restrict__ bin0,
    float* __restrict__ bcat)
{
  __shared__ float tile[64][65];
  const int bid = blockIdx.x, tid = threadIdx.x;
  if (bid < 6720) {
    const float* src; ushort_t* dst; long i;
    if (bid < 1152)      { src = Win;   dst = Winb; i = (long)bid * 256 + tid; }
    else if (bid < 1216) { src = Wemb;  dst = Wq0;  i = (long)(bid - 1152) * 256 + tid; }
    else if (bid < 1600) { src = Wconv; dst = Wcb;  i = (long)(bid - 1216) * 256 + tid; }
    else if (bid < 5696) { src = ADJ;   dst = ADJb; i = (long)(bid - 1600) * 256 + tid; }
    else                 { src = CF;    dst = CFb;  i = (long)(bid - 5696) * 256 + tid; }
    floatx4 a = ((const floatx4*)src)[2 * i];
    floatx4 b = ((const floatx4*)src)[2 * i + 1];
    ushortx4 ha, hb;
#pragma unroll
    for (int r = 0; r < 4; ++r) { ha[r] = f2b(a[r]); hb[r] = f2b(b[r]); }
    ((ushortx4*)dst)[2 * i] = ha; ((ushortx4*)dst)[2 * i + 1] = hb;
  } else if (bid < 6912) {
    // transpose+cvt: T[l][k][j] = bf16(Wout[l][j][k])
    const int t = bid - 6720;
    const int z = t >> 6, k0 = ((t >> 3) & 7) * 64, j0 = (t & 7) * 64;
    const long base = (long)z * 262144;
#pragma unroll
    for (int p = 0; p < 16; ++p) {
      int idx = tid + p * 256;
      int jj = idx >> 6, kk = idx & 63;
      tile[jj][kk] = Wout[base + (long)(j0 + jj) * 512 + k0 + kk];
    }
    __syncthreads();
#pragma unroll
    for (int p = 0; p < 16; ++p) {
      int idx = tid + p * 256;
      int kk = idx >> 6, jj = idx & 63;
      WoT[base + (long)(k0 + kk) * 512 + j0 + jj] = f2b(tile[jj][kk]);
    }
  } else if (bid < 6944) {
    // WembT[c][h] = bf16(Wemb[h][c])  (Wemb is [512][256])
    const int t = bid - 6912;
    const int j0 = (t >> 2) * 64, k0 = (t & 3) * 64;
#pragma unroll
    for (int p = 0; p < 16; ++p) {
      int idx = tid + p * 256;
      int jj = idx >> 6, kk = idx & 63;
      tile[jj][kk] = Wemb[(long)(j0 + jj) * 256 + k0 + kk];
    }
    __syncthreads();
#pragma unroll
    for (int p = 0; p < 16; ++p) {
      int idx = tid + p * 256;
      int kk = idx >> 6, jj = idx & 63;
      WembT[(long)(k0 + kk) * 512 + j0 + jj] = f2b(tile[jj][kk]);
    }
  } else if (bid < 7328) {
    // bfused[l][o] = dot(Wconv[l][o][:], bout[l][:]) + bconv[l][o]
    const int w = tid >> 6, lane = tid & 63;
    const int gi = (bid - 6944) * 4 + w;
    const int l = gi >> 9, o = gi & 511;
    float p = 0.f;
#pragma unroll
    for (int k = 0; k < 8; ++k)
      p += Wconv[(long)l * 262144 + (long)o * 512 + lane + 64 * k] *
           bout[l * 512 + lane + 64 * k];
#pragma unroll
    for (int msk = 1; msk <= 32; msk <<= 1) p += __shfl_xor(p, msk);
    if (lane == 0) bfused[gi] = p + bconv[l * 512 + o];
  } else if (bid < 7712) {
    // bcat[512+o] = bin0[o] + dot(Win0[o][:], bemb[:])  (layer-0 bias fold)
    const int w = tid >> 6, lane = tid & 63;
    const int o = (bid - 7328) * 4 + w;
    float p = 0.f;
#pragma unroll
    for (int k = 0; k < 8; ++k)
      p += Win[(long)o * 512 + lane + 64 * k] * bemb[lane + 64 * k];
#pragma unroll
    for (int msk = 1; msk <= 32; msk <<= 1) p += __shfl_xor(p, msk);
    if (lane == 0) bcat[512 + o] = p + bin0[o];
  } else {
    // bcat[0:512] = bemb
    int idx = (bid - 7712) * 256 + tid;
    bcat[idx] = bemb[idx];
  }
}

// =========================================================================
// Attention over batch axis. Block (512 thr) per node n; qkv staged in LDS
// as bf16 (source already bf16 -> lossless), ~27 KB -> 4 blocks/CU, grid
// 1024 fully resident. Wave = head. Stride 1544 puts the 8 Q/K row bases
// on 8 distinct banks.
// =========================================================================
__global__ __launch_bounds__(512, 8) void attn_kernel(
    const ushort_t* __restrict__ qkv, ushort_t* __restrict__ outp)
{
  __shared__ ushort_t qs[8 * 1544];
  __shared__ float aw[8][64];
  const int tid = threadIdx.x;
  const int n = blockIdx.x;

  const ushort_t* src = qkv + (long)n * 1536;
#pragma unroll
  for (int p = 0; p < 3; ++p) {
    int c = tid + p * 512;
    int i = c / 192, off = (c % 192) * 8;
    *(ushortx8*)(&qs[i * 1544 + off]) =
        *(const ushortx8*)(src + (long)i * 1024 * 1536 + off);
  }
  __syncthreads();

  const int h    = tid >> 6;
  const int lane = tid & 63;
  const int i = lane >> 3, j = lane & 7;
  const ushort_t* qrow = &qs[i * 1544 + h * 64];
  const ushort_t* krow = &qs[j * 1544 + 512 + h * 64];
  float s = 0.f;
#pragma unroll
  for (int c8 = 0; c8 < 8; ++c8) {
    ushortx8 qa = *(const ushortx8*)(qrow + c8 * 8);
    ushortx8 ka = *(const ushortx8*)(krow + c8 * 8);
#pragma unroll
    for (int r = 0; r < 8; ++r) s += b2f(qa[r]) * b2f(ka[r]);
  }
  s *= 0.125f;

  float m = s;
  m = fmaxf(m, __shfl_xor(m, 1));
  m = fmaxf(m, __shfl_xor(m, 2));
  m = fmaxf(m, __shfl_xor(m, 4));
  float e = __expf(s - m);
  float sum = e;
  sum += __shfl_xor(sum, 1);
  sum += __shfl_xor(sum, 2);
  sum += __shfl_xor(sum, 4);
  aw[h][lane] = e / sum;   // written+read by the same wave; no barrier needed

  // PV: hoist v into regs (channel = h*64 + lane)
  float vv[8];
#pragma unroll
  for (int jj = 0; jj < 8; ++jj)
    vv[jj] = b2f(qs[jj * 1544 + 1024 + h * 64 + lane]);
  const long ob = (long)n * 512 + h * 64 + lane;
#pragma unroll
  for (int ii = 0; ii < 8; ++ii) {
    float acc = 0.f;
#pragma unroll
    for (int jj = 0; jj < 8; ++jj) acc += aw[h][ii * 8 + jj] * vv[jj];
    outp[ob + (long)ii * 1024 * 512] = f2b(acc);
  }
}

// =========================================================================
// x_out(bf16) = LayerNorm(x + aggA+aggB). Wave per row (512).
// =========================================================================
__global__ __launch_bounds__(256) void ln_kernel(
    const ushort_t* __restrict__ xb,
    const ushort_t* __restrict__ aggA, const ushort_t* __restrict__ aggB,
    ushort_t* __restrict__ outB)
{
  const int w = threadIdx.x >> 6, lane = threadIdx.x & 63;
  const long base = ((long)blockIdx.x * 4 + w) * 512;
  float v[8];
  float s = 0.f;
#pragma unroll
  for (int k = 0; k < 8; ++k) {
    long idx = base + lane + 64 * k;
    v[k] = b2f(xb[idx]) + b2f(aggA[idx]) + b2f(aggB[idx]);
    s += v[k];
  }
#pragma unroll
  for (int msk = 1; msk <= 32; msk <<= 1) s += __shfl_xor(s, msk);
  float mean = s * (1.f / 512.f);
  float vv = 0.f;
#pragma unroll
  for (int k = 0; k < 8; ++k) { float d = v[k] - mean; vv += d * d; }
#pragma unroll
  for (int msk = 1; msk <= 32; msk <<= 1) vv += __shfl_xor(vv, msk);
  float inv = rsqrtf(vv * (1.f / 512.f) + 1e-5f);
#pragma unroll
  for (int k = 0; k < 8; ++k)
    outB[base + lane + 64 * k] = f2b((v[k] - mean) * inv);
}

// =========================================================================
// Final layer: LN -> out_x (fp32) + fused heads (mastery, diff, h1, h2)
// + per-block pool partials xp[2048][512] (for graph pooling).
// =========================================================================
__global__ __launch_bounds__(256) void final_ln_heads_kernel(
    const ushort_t* __restrict__ xb,
    const ushort_t* __restrict__ aggA, const ushort_t* __restrict__ aggB,
    float* __restrict__ out_x,
    const float* __restrict__ Wcls, const float* __restrict__ bcls,
    const float* __restrict__ Wdiff, const float* __restrict__ bdiff,
    const float* __restrict__ Wpre,
    float* __restrict__ mastery, float* __restrict__ diff,
    float* __restrict__ h1, float* __restrict__ h2,
    float* __restrict__ xp)
{
  __shared__ float sp4[4][512];
  const int w = threadIdx.x >> 6, lane = threadIdx.x & 63;
  const long row = (long)blockIdx.x * 4 + w;
  const long base = row * 512;
  float v[8];
  float s = 0.f;
#pragma unroll
  for (int k = 0; k < 8; ++k) {
    long idx = base + lane + 64 * k;
    v[k] = b2f(xb[idx]) + b2f(aggA[idx]) + b2f(aggB[idx]);
    s += v[k];
  }
#pragma unroll
  for (int msk = 1; msk <= 32; msk <<= 1) s += __shfl_xor(s, msk);
  float mean = s * (1.f / 512.f);
  float vv = 0.f;
#pragma unroll
  for (int k = 0; k < 8; ++k) { float d = v[k] - mean; vv += d * d; }
#pragma unroll
  for (int msk = 1; msk <= 32; msk <<= 1) vv += __shfl_xor(vv, msk);
  float inv = rsqrtf(vv * (1.f / 512.f) + 1e-5f);
#pragma unroll
  for (int k = 0; k < 8; ++k) {
    v[k] = (v[k] - mean) * inv;
    out_x[base + lane + 64 * k] = v[k];
    sp4[w][lane + 64 * k] = v[k];
  }
  __syncthreads();
  // block pool partial: sum of this block's 4 rows (256 blocks/batch)
  for (int t = threadIdx.x; t < 512; t += 256)
    xp[(long)blockIdx.x * 512 + t] =
        sp4[0][t] + sp4[1][t] + sp4[2][t] + sp4[3][t];
#pragma unroll
  for (int o = 0; o < 8; ++o) {
    const float* wp = (o == 0) ? Wcls
                    : (o <= 5) ? (Wdiff + (o - 1) * 512)
                    : (o == 6) ? Wpre : (Wpre + 512);
    float p = 0.f;
#pragma unroll
    for (int k = 0; k < 8; ++k) p += v[k] * wp[lane + 64 * k];
#pragma unroll
    for (int msk = 1; msk <= 32; msk <<= 1) p += __shfl_xor(p, msk);
    if (lane == 0) {
      if (o == 0)      mastery[row] = p + bcls[0];
      else if (o <= 5) diff[row * 5 + (o - 1)] = p + bdiff[o - 1];
      else if (o == 6) h1[row] = p;
      else             h2[row] = p;
    }
  }
}

// =========================================================================
// epilogue fused: [0,2048) prereq (4 rows each), [2048,2056) pool+graph
// (one block per batch: xm in LDS from xp, then graph = xm/1024 @ Wpool^T).
// =========================================================================
__global__ __launch_bounds__(256) void epi_kernel(
    const float* __restrict__ h1, const float* __restrict__ h2,
    const float* __restrict__ bpre, float* __restrict__ outp,
    const float* __restrict__ xp, const float* __restrict__ Wpool,
    const float* __restrict__ bpool, float* __restrict__ g)
{
  __shared__ float xms[512];
  const int bid = blockIdx.x;
  if (bid < 2048) {
#pragma unroll
    for (int rr = 0; rr < 4; ++rr) {
      const int ri = bid * 4 + rr;
      const int b = ri >> 10, i = ri & 1023;
      const float base = h1[ri] + bpre[0];
      const long ob = (long)b * (1024 * 1023) + (long)i * 1023;
      const float* h2b = h2 + b * 1024;
#pragma unroll
      for (int r = 0; r < 4; ++r) {
        int j = r * 256 + threadIdx.x;
        if (j == i) continue;
        int pos = (j < i) ? j : j - 1;
        outp[ob + pos] = base + h2b[j];
      }
    }
  } else {
    const int b = bid - 2048;
    const float* p = xp + (long)b * 256 * 512;
#pragma unroll
    for (int cc = 0; cc < 2; ++cc) {
      int c = threadIdx.x + cc * 256;
      float s = 0.f;
      for (int q = 0; q < 256; ++q) s += p[q * 512 + c];
      xms[c] = s;
    }
    __syncthreads();
#pragma unroll
    for (int oo = 0; oo < 2; ++oo) {
      int o = threadIdx.x + oo * 256;
      const float* wr = Wpool + (long)o * 512;
      float s = 0.f;
      for (int hh = 0; hh < 512; ++hh) s += xms[hh] * wr[hh];
      g[b * 512 + o] = s * (1.f / 1024.f) + bpool[o];
    }
  }
}

// =========================================================================
extern "C" void kernel_launch(void* const* d_in, const int* in_sizes, int n_in,
                              void* d_out, int out_size, void* d_ws, size_t ws_size,
                              hipStream_t stream)
{
  const float* CF    = (const float*)d_in[0];
  const float* ADJ   = (const float*)d_in[1];
  const float* Wemb  = (const float*)d_in[4];
  const float* bemb  = (const float*)d_in[5];
  const float* Win   = (const float*)d_in[6];
  const float* bin   = (const float*)d_in[7];
  const float* Wout  = (const float*)d_in[8];
  const float* bout  = (const float*)d_in[9];
  const float* Wconv = (const float*)d_in[10];
  const float* bconv = (const float*)d_in[11];
  const float* Wcls  = (const float*)d_in[12];
  const float* bcls  = (const float*)d_in[13];
  const float* Wdiff = (const float*)d_in[14];
  const float* bdiff = (const float*)d_in[15];
  const float* Wpre  = (const float*)d_in[16];
  const float* bpre  = (const float*)d_in[17];
  const float* Wpool = (const float*)d_in[18];
  const float* bpool = (const float*)d_in[19];

  // ---- workspace layout (ushort units). Total ~70.4 MB (< proven 84 MB). ----
  ushort_t* W = (ushort_t*)d_ws;
  ushort_t* xb   = W;                       // 4194304
  ushort_t* qkvb = W + 4194304;             // 12582912 (end 16777216)
  // aliases inside the qkv region (dead when their user runs):
  ushort_t* cT    = qkvb;                   // 4194304 (conv out, post-attn)
  ushort_t* aggA  = qkvb + 4194304;         // 4194304 (split-K part 0)
  ushort_t* aggB  = qkvb + 8388608;         // 4194304 (split-K part 1)
  // precompute scratch overlays aggA/B region (dead before qkv0 GEMM):
  ushort_t* WoT   = qkvb + 4194304;         // 786432
  ushort_t* Wcb   = qkvb + 4980736;         // 786432
  ushort_t* WembT = qkvb + 5767168;         // 131072 (end 5898240 < 8388608)
  // persistent:
  ushort_t* Winb = W + 16777216;            // 2359296
  ushort_t* Wfb  = W + 19136512;            // 786432 (fused Wconv@Wout)
  ushort_t* ADJb = W + 19922944;            // 8388608 (end 28311552)
  ushort_t* CFb  = W + 28311552;            // 4194304 (end 32505856)
  ushort_t* Wq0  = W + 32505856;            // 524288 (rows 0-511 Wemb, 512-2047 Win0@Wemb)
  float* bfused = (float*)(W + 33030144);   // 1536
  float* bcat   = bfused + 1536;            // 2048 (bemb ++ folded qkv0 bias)
  float* h1     = bcat + 2048;              // 8192
  float* h2     = h1 + 8192;                // 8192
  float* xp     = h2 + 8192;                // 1048576 (pool partials)

  // ---- output layout (fp32 concat) + d_out-as-scratch aliases ----
  float* out_x       = (float*)d_out;       // 4194304
  float* out_mastery = out_x + 4194304;     // 8192
  float* out_diff    = out_mastery + 8192;  // 40960
  float* out_prereq  = out_diff + 40960;    // 8380416
  float* out_graph   = out_prereq + 8380416;// 4096
  // attn-out bf16 scratch in out_x region (dead before final LN writes it):
  ushort_t* aob = (ushort_t*)out_x;         // 4194304 ushorts

  dim3 blk(256);

  // ---- precompute: one dispatch + one merged setup-GEMM dispatch ----
  prep_kernel<<<dim3(7714), blk, 0, stream>>>(
      Win, Winb, Wemb, Wq0, Wconv, Wcb, ADJ, ADJb, CF, CFb,
      Wout, WoT, bout, bconv, bfused, WembT, bemb, bin, bcat);
  setup_gemm<<<dim3(24, 1, 4), blk, 0, stream>>>(
      Wcb, WoT, Wfb, Winb, WembT, Wq0 + 512 * 256);

  for (int l = 0; l < 3; ++l) {
    // qkv = x @ Win[l]^T + bin[l]
    if (l == 0) {
      // fused x0|qkv0: [xb | qkvb] = CFb @ Wq0^T + bcat  (8192 x 2048 x 256)
      gemm_bt<3, 1><<<dim3(16, 64, 1), blk, 0, stream>>>(
          CFb, Wq0, bcat, xb, qkvb, 2048, 256, 0, 0, 0);
    } else {
      gemm_bt<1, 1><<<dim3(12, 64, 1), blk, 0, stream>>>(
          xb, Winb + (long)l * 786432, bin + l * 1536,
          qkvb, nullptr, 1536, 512, 0, 0, 0);
    }
    // attention over batch axis -> aob (out_x scratch)
    attn_kernel<<<dim3(1024), dim3(512), 0, stream>>>(qkvb, aob);
    // convT = (ao @ Wfused[l]^T + bfused[l]) transposed (qkv region dead)
    gemm_bt<2, 1><<<dim3(4, 64, 1), blk, 0, stream>>>(
        aob, Wfb + (long)l * 262144, bfused + l * 512,
        cT, nullptr, 512, 512, 0, 0, 0);
    // agg[b] = adj[b] @ conv[b]  (batched 1024x512x1024, split-K=2, bf16)
    gemm_bt<1, 2><<<dim3(4, 8, 16), blk, 0, stream>>>(
        ADJb, cT, nullptr, aggA, aggB,
        512, 1024, 1048576, 524288, 524288);
    // x = LN(x + aggA + aggB)
    if (l < 2)
      ln_kernel<<<dim3(2048), blk, 0, stream>>>(xb, aggA, aggB, xb);
    else
      final_ln_heads_kernel<<<dim3(2048), blk, 0, stream>>>(
          xb, aggA, aggB, out_x, Wcls, bcls, Wdiff, bdiff, Wpre,
          out_mastery, out_diff, h1, h2, xp);
  }

  epi_kernel<<<dim3(2056), blk, 0, stream>>>(h1, h2, bpre, out_prereq,
                                             xp, Wpool, bpool, out_graph);
}

// Round 4
// 423.321 us; speedup vs baseline: 1.0844x; 1.0226x over previous
//
#include <hip/hip_runtime.h>
#include <hip/hip_bf16.h>

typedef unsigned short ushort_t;
typedef __attribute__((ext_vector_type(4))) float floatx4;
typedef __attribute__((ext_vector_type(8))) __bf16 bf16x8;
typedef __attribute__((ext_vector_type(4))) unsigned short ushortx4;
typedef __attribute__((ext_vector_type(8))) unsigned short ushortx8;

// ---------- bf16 helpers ----------
static __device__ __forceinline__ float b2f(ushort_t u) {
  union { unsigned int i; float f; } v; v.i = ((unsigned int)u) << 16; return v.f;
}
static __device__ __forceinline__ ushort_t f2b(float f) {
  unsigned int x = __float_as_uint(f);
  unsigned int r = (x + 0x7fffu + ((x >> 16) & 1u)) >> 16;
  return (ushort_t)r;
}
// async global->LDS, 16B per lane (dest = wave-uniform base + lane*16)
static __device__ __forceinline__ void glds16(const ushort_t* g, ushort_t* l) {
  __builtin_amdgcn_global_load_lds(
      (const __attribute__((address_space(1))) unsigned int*)g,
      (__attribute__((address_space(3))) unsigned int*)l, 16, 0, 0);
}

// =========================================================================
// GEMM core: C[m0:+128, n0:+128] = A[M,K] @ B[N,K]^T (+bias[col]).
// bf16 MFMA, tile 128x128xBK64, 4 waves, wave 64x64 via 4x4 mfma 16x16x32.
// LDS bank-conflict fix: k-chunk XOR swizzle (slot c holds chunk c^(row&7)).
// MODE 1: bf16 row-major [M,N] (caller folds batch offset into outB)
// MODE 2: bf16 TRANSPOSED batched: [(b*N+col)*1024 + (m&1023)], b=m>>10
// MODE 3: split-N: cols [0,512)->outB stride 512; [512,2048)->C1 stride 1536
// =========================================================================
template<int MODE>
static __device__ __forceinline__ void gemm_core(
    const ushort_t* __restrict__ Ab, const ushort_t* __restrict__ Bm,
    const float* __restrict__ bias,
    ushort_t* __restrict__ outB, ushort_t* __restrict__ C1,
    int N, int K, int m0, int n0, int kbeg, int kend,
    ushort_t* As, ushort_t* Bs)
{
  const int tid  = threadIdx.x;
  const int wid  = tid >> 6;
  const int lane = tid & 63;
  const int quad = lane >> 4;
  const int l16  = lane & 15;

  const int wr = (wid >> 1) * 64;
  const int wc = (wid & 1) * 64;

  // staging: thread covers LDS slot (srow, tid&7); global source chunk is
  // XOR-swizzled: scj = (tid&7) ^ (srow&7)
  const int srow = tid >> 3;
  const int scj  = ((tid & 7) ^ (srow & 7)) * 8;
  const long abase = (long)(m0 + srow) * K + scj;
  const long bbase = (long)(n0 + srow) * K + scj;

  floatx4 acc[4][4];
#pragma unroll
  for (int i = 0; i < 4; ++i)
#pragma unroll
    for (int j = 0; j < 4; ++j) acc[i][j] = (floatx4){0.f, 0.f, 0.f, 0.f};

  const int rx = l16 & 7;   // row&7 for all fragment rows (wr,wc,i*16 mult 8)

  for (int k0 = kbeg; k0 < kend; k0 += 64) {
    __syncthreads();
#pragma unroll
    for (int p = 0; p < 4; ++p)
      glds16(Ab + abase + 32 * p * (long)K + k0, &As[tid * 8 + p * 2048]);
#pragma unroll
    for (int p = 0; p < 4; ++p)
      glds16(Bm + bbase + 32 * p * (long)K + k0, &Bs[tid * 8 + p * 2048]);
    __syncthreads();

#pragma unroll
    for (int kk = 0; kk < 2; ++kk) {
      bf16x8 a[4], b[4];
#pragma unroll
      for (int i = 0; i < 4; ++i)
        a[i] = *(const bf16x8*)(&As[(wr + i * 16 + l16) * 64 +
                                    (((kk * 4 + quad) ^ rx) << 3)]);
#pragma unroll
      for (int j = 0; j < 4; ++j)
        b[j] = *(const bf16x8*)(&Bs[(wc + j * 16 + l16) * 64 +
                                    (((kk * 4 + quad) ^ rx) << 3)]);
#pragma unroll
      for (int i = 0; i < 4; ++i)
#pragma unroll
        for (int j = 0; j < 4; ++j)
          acc[i][j] = __builtin_amdgcn_mfma_f32_16x16x32_bf16(a[i], b[j], acc[i][j], 0, 0, 0);
    }
  }

  // epilogue: lane = col l16; rows quad*4+r in each 16x16 sub-tile
#pragma unroll
  for (int j = 0; j < 4; ++j) {
    int col = n0 + wc + j * 16 + l16;
    float bv = (bias != nullptr) ? bias[col] : 0.f;
#pragma unroll
    for (int i = 0; i < 4; ++i) {
      int mbase = m0 + wr + i * 16 + quad * 4;
      if constexpr (MODE == 1) {
#pragma unroll
        for (int r = 0; r < 4; ++r)
          outB[(long)(mbase + r) * N + col] = f2b(acc[i][j][r] + bv);
      } else if constexpr (MODE == 2) {
        int b = mbase >> 10, jrow = mbase & 1023;
        ushortx4 pk;
#pragma unroll
        for (int r = 0; r < 4; ++r) pk[r] = f2b(acc[i][j][r] + bv);
        *(ushortx4*)(outB + ((long)b * N + col) * 1024 + jrow) = pk;
      } else {
        // MODE 3: fused x0|qkv0 split-N (n-tiles are 128-wide, so a whole
        // block is on one side of col 512)
        ushort_t* o = (n0 < 512) ? outB : C1;
        const int cw = (n0 < 512) ? 512 : 1536;
        const int cc = (n0 < 512) ? col : col - 512;
#pragma unroll
        for (int r = 0; r < 4; ++r)
          o[(long)(mbase + r) * cw + cc] = f2b(acc[i][j][r] + bv);
      }
    }
  }
}

// generic dispatcher: XCD swizzle lin = y*gridX+x; m = lin%gridY, n = lin/gridY
// KS: split-K ways; blockIdx.z = z*KS+kq; partial kq -> C{kq}.
template<int MODE, int KS>
__global__ __launch_bounds__(256, 3) void gemm_bt(
    const ushort_t* __restrict__ Ab, const ushort_t* __restrict__ Bm,
    const float* __restrict__ bias,
    ushort_t* __restrict__ C0, ushort_t* __restrict__ C1,
    int N, int K, long aBatch, long bBatch, long cBatch)
{
  __shared__ __align__(16) ushort_t As[128 * 64];
  __shared__ __align__(16) ushort_t Bs[128 * 64];
  const int lin = blockIdx.y * gridDim.x + blockIdx.x;
  const int m0 = (lin % gridDim.y) * 128;
  const int n0 = (lin / gridDim.y) * 128;
  const int z  = (KS > 1) ? (int)(blockIdx.z / KS) : blockIdx.z;
  const int kq = (KS > 1) ? (int)(blockIdx.z % KS) : 0;
  const int kbeg = kq * (K / KS);
  const int kend = kbeg + (K / KS);
  ushort_t* outB = (KS >= 2 && kq == 1) ? C1 : C0;
  gemm_core<MODE>(Ab + (long)z * aBatch, Bm + (long)z * bBatch, bias,
                  outB + ((MODE == 1) ? (long)z * cBatch : 0), C1,
                  N, K, m0, n0, kbeg, kend, As, Bs);
}

// setup GEMMs merged: z<3 -> Wfused[z] = Wconv[z] @ Wout[z] (512x512x512);
// z==3 -> Wq0 tail = Win0 @ Wemb (1536x256x512). Grid (24,1,4).
__global__ __launch_bounds__(256, 3) void setup_gemm(
    const ushort_t* __restrict__ Wcb, const ushort_t* __restrict__ WoT,
    ushort_t* __restrict__ Wfb,
    const ushort_t* __restrict__ Winb, const ushort_t* __restrict__ WembT,
    ushort_t* __restrict__ Wq0t)
{
  __shared__ __align__(16) ushort_t As[128 * 64];
  __shared__ __align__(16) ushort_t Bs[128 * 64];
  const int lin = blockIdx.x;
  const int z = blockIdx.z;
  if (z < 3) {
    if (lin >= 16) return;   // block-uniform exit, before any barrier
    const long off = (long)z * 262144;
    gemm_core<1>(Wcb + off, WoT + off, nullptr, Wfb + off, nullptr,
                 512, 512, (lin & 3) * 128, (lin >> 2) * 128, 0, 512, As, Bs);
  } else {
    gemm_core<1>(Winb, WembT, nullptr, Wq0t, nullptr,
                 256, 512, (lin % 12) * 128, (lin / 12) * 128, 0, 512, As, Bs);
  }
}

// =========================================================================
// prep (one dispatch): fp32->bf16 conversions (Win, Wemb->Wq0 head, Wconv,
// ADJ, CF), Wout transpose, Wemb transpose, bfused, folded layer-0 bias,
// Wpool fp32 transpose.
// blocks: [0,1152) Win | [1152,1216) Wemb->Wq0 | [1216,1600) Wconv |
// [1600,5696) ADJ | [5696,6720) CF | [6720,6912) WoutT | [6912,6944) WembT |
// [6944,7328) bfuse | [7328,7712) bfq->bcat+512 | [7712,7714) bemb->bcat |
// [7714,7778) WpoolT
// =========================================================================
__global__ __launch_bounds__(256) void prep_kernel(
    const float* __restrict__ Win,  ushort_t* __restrict__ Winb,
    const float* __restrict__ Wemb, ushort_t* __restrict__ Wq0,
    const float* __restrict__ Wconv, ushort_t* __restrict__ Wcb,
    const float* __restrict__ ADJ,  ushort_t* __restrict__ ADJb,
    const float* __restrict__ CF,   ushort_t* __restrict__ CFb,
    const float* __restrict__ Wout, ushort_t* __restrict__ WoT,
    const float* __restrict__ bout, const float* __restrict__ bconv,
    float* __restrict__ bfused,
    ushort_t* __restrict__ WembT,
    const float* __restrict__ bemb, const float* __restrict__ bin0,
    float* __restrict__ bcat,
    const float* __restrict__ Wpool, float* __restrict__ WpT)
{
  __shared__ float tile[64][65];
  const int bid = blockIdx.x, tid = threadIdx.x;
  if (bid < 6720) {
    const float* src; ushort_t* dst; long i;
    if (bid < 1152)      { src = Win;   dst = Winb; i = (long)bid * 256 + tid; }
    else if (bid < 1216) { src = Wemb;  dst = Wq0;  i = (long)(bid - 1152) * 256 + tid; }
    else if (bid < 1600) { src = Wconv; dst = Wcb;  i = (long)(bid - 1216) * 256 + tid; }
    else if (bid < 5696) { src = ADJ;   dst = ADJb; i = (long)(bid - 1600) * 256 + tid; }
    else                 { src = CF;    dst = CFb;  i = (long)(bid - 5696) * 256 + tid; }
    floatx4 a = ((const floatx4*)src)[2 * i];
    floatx4 b = ((const floatx4*)src)[2 * i + 1];
    ushortx4 ha, hb;
#pragma unroll
    for (int r = 0; r < 4; ++r) { ha[r] = f2b(a[r]); hb[r] = f2b(b[r]); }
    ((ushortx4*)dst)[2 * i] = ha; ((ushortx4*)dst)[2 * i + 1] = hb;
  } else if (bid < 6912) {
    // transpose+cvt: T[l][k][j] = bf16(Wout[l][j][k])
    const int t = bid - 6720;
    const int z = t >> 6, k0 = ((t >> 3) & 7) * 64, j0 = (t & 7) * 64;
    const long base = (long)z * 262144;
#pragma unroll
    for (int p = 0; p < 16; ++p) {
      int idx = tid + p * 256;
      int jj = idx >> 6, kk = idx & 63;
      tile[jj][kk] = Wout[base + (long)(j0 + jj) * 512 + k0 + kk];
    }
    __syncthreads();
#pragma unroll
    for (int p = 0; p < 16; ++p) {
      int idx = tid + p * 256;
      int kk = idx >> 6, jj = idx & 63;
      WoT[base + (long)(k0 + kk) * 512 + j0 + jj] = f2b(tile[jj][kk]);
    }
  } else if (bid < 6944) {
    // WembT[c][h] = bf16(Wemb[h][c])  (Wemb is [512][256])
    const int t = bid - 6912;
    const int j0 = (t >> 2) * 64, k0 = (t & 3) * 64;
#pragma unroll
    for (int p = 0; p < 16; ++p) {
      int idx = tid + p * 256;
      int jj = idx >> 6, kk = idx & 63;
      tile[jj][kk] = Wemb[(long)(j0 + jj) * 256 + k0 + kk];
    }
    __syncthreads();
#pragma unroll
    for (int p = 0; p < 16; ++p) {
      int idx = tid + p * 256;
      int kk = idx >> 6, jj = idx & 63;
      WembT[(long)(k0 + kk) * 512 + j0 + jj] = f2b(tile[jj][kk]);
    }
  } else if (bid < 7328) {
    // bfused[l][o] = dot(Wconv[l][o][:], bout[l][:]) + bconv[l][o]
    const int w = tid >> 6, lane = tid & 63;
    const int gi = (bid - 6944) * 4 + w;
    const int l = gi >> 9, o = gi & 511;
    float p = 0.f;
#pragma unroll
    for (int k = 0; k < 8; ++k)
      p += Wconv[(long)l * 262144 + (long)o * 512 + lane + 64 * k] *
           bout[l * 512 + lane + 64 * k];
#pragma unroll
    for (int msk = 1; msk <= 32; msk <<= 1) p += __shfl_xor(p, msk);
    if (lane == 0) bfused[gi] = p + bconv[l * 512 + o];
  } else if (bid < 7712) {
    // bcat[512+o] = bin0[o] + dot(Win0[o][:], bemb[:])  (layer-0 bias fold)
    const int w = tid >> 6, lane = tid & 63;
    const int o = (bid - 7328) * 4 + w;
    float p = 0.f;
#pragma unroll
    for (int k = 0; k < 8; ++k)
      p += Win[(long)o * 512 + lane + 64 * k] * bemb[lane + 64 * k];
#pragma unroll
    for (int msk = 1; msk <= 32; msk <<= 1) p += __shfl_xor(p, msk);
    if (lane == 0) bcat[512 + o] = p + bin0[o];
  } else if (bid < 7714) {
    // bcat[0:512] = bemb
    int idx = (bid - 7712) * 256 + tid;
    bcat[idx] = bemb[idx];
  } else {
    // WpT[h][o] = Wpool[o][h]  (fp32, for coalesced graph dot)
    const int t = bid - 7714;
    const int j0 = (t >> 3) * 64, k0 = (t & 7) * 64;   // j=o tile, k=h tile
#pragma unroll
    for (int p = 0; p < 16; ++p) {
      int idx = tid + p * 256;
      int jj = idx >> 6, kk = idx & 63;
      tile[jj][kk] = Wpool[(long)(j0 + jj) * 512 + k0 + kk];
    }
    __syncthreads();
#pragma unroll
    for (int p = 0; p < 16; ++p) {
      int idx = tid + p * 256;
      int kk = idx >> 6, jj = idx & 63;
      WpT[(long)(k0 + kk) * 512 + j0 + jj] = tile[jj][kk];
    }
  }
}

// =========================================================================
// Attention over batch axis. Block (512 thr) per node n; qkv staged in LDS
// as bf16 (source already bf16 -> lossless), ~27 KB -> 4 blocks/CU, grid
// 1024 fully resident. Wave = head. Stride 1544 puts the 8 Q/K row bases
// on 8 distinct banks.
// =========================================================================
__global__ __launch_bounds__(512, 8) void attn_kernel(
    const ushort_t* __restrict__ qkv, ushort_t* __restrict__ outp)
{
  __shared__ ushort_t qs[8 * 1544];
  __shared__ float aw[8][64];
  const int tid = threadIdx.x;
  const int n = blockIdx.x;

  const ushort_t* src = qkv + (long)n * 1536;
#pragma unroll
  for (int p = 0; p < 3; ++p) {
    int c = tid + p * 512;
    int i = c / 192, off = (c % 192) * 8;
    *(ushortx8*)(&qs[i * 1544 + off]) =
        *(const ushortx8*)(src + (long)i * 1024 * 1536 + off);
  }
  __syncthreads();

  const int h    = tid >> 6;
  const int lane = tid & 63;
  const int i = lane >> 3, j = lane & 7;
  const ushort_t* qrow = &qs[i * 1544 + h * 64];
  const ushort_t* krow = &qs[j * 1544 + 512 + h * 64];
  float s = 0.f;
#pragma unroll
  for (int c8 = 0; c8 < 8; ++c8) {
    ushortx8 qa = *(const ushortx8*)(qrow + c8 * 8);
    ushortx8 ka = *(const ushortx8*)(krow + c8 * 8);
#pragma unroll
    for (int r = 0; r < 8; ++r) s += b2f(qa[r]) * b2f(ka[r]);
  }
  s *= 0.125f;

  float m = s;
  m = fmaxf(m, __shfl_xor(m, 1));
  m = fmaxf(m, __shfl_xor(m, 2));
  m = fmaxf(m, __shfl_xor(m, 4));
  float e = __expf(s - m);
  float sum = e;
  sum += __shfl_xor(sum, 1);
  sum += __shfl_xor(sum, 2);
  sum += __shfl_xor(sum, 4);
  aw[h][lane] = e / sum;   // written+read by the same wave; no barrier needed

  // PV: hoist v into regs (channel = h*64 + lane)
  float vv[8];
#pragma unroll
  for (int jj = 0; jj < 8; ++jj)
    vv[jj] = b2f(qs[jj * 1544 + 1024 + h * 64 + lane]);
  const long ob = (long)n * 512 + h * 64 + lane;
#pragma unroll
  for (int ii = 0; ii < 8; ++ii) {
    float acc = 0.f;
#pragma unroll
    for (int jj = 0; jj < 8; ++jj) acc += aw[h][ii * 8 + jj] * vv[jj];
    outp[ob + (long)ii * 1024 * 512] = f2b(acc);
  }
}

// =========================================================================
// x_out(bf16) = LayerNorm(x + aggA+aggB). Wave per row (512).
// =========================================================================
__global__ __launch_bounds__(256) void ln_kernel(
    const ushort_t* __restrict__ xb,
    const ushort_t* __restrict__ aggA, const ushort_t* __restrict__ aggB,
    ushort_t* __restrict__ outB)
{
  const int w = threadIdx.x >> 6, lane = threadIdx.x & 63;
  const long base = ((long)blockIdx.x * 4 + w) * 512;
  float v[8];
  float s = 0.f;
#pragma unroll
  for (int k = 0; k < 8; ++k) {
    long idx = base + lane + 64 * k;
    v[k] = b2f(xb[idx]) + b2f(aggA[idx]) + b2f(aggB[idx]);
    s += v[k];
  }
#pragma unroll
  for (int msk = 1; msk <= 32; msk <<= 1) s += __shfl_xor(s, msk);
  float mean = s * (1.f / 512.f);
  float vv = 0.f;
#pragma unroll
  for (int k = 0; k < 8; ++k) { float d = v[k] - mean; vv += d * d; }
#pragma unroll
  for (int msk = 1; msk <= 32; msk <<= 1) vv += __shfl_xor(vv, msk);
  float inv = rsqrtf(vv * (1.f / 512.f) + 1e-5f);
#pragma unroll
  for (int k = 0; k < 8; ++k)
    outB[base + lane + 64 * k] = f2b((v[k] - mean) * inv);
}

// =========================================================================
// Final layer: LN -> out_x (fp32) + fused heads (mastery, diff, h1, h2)
// + per-block pool partials xp[2048][512] (for graph pooling).
// =========================================================================
__global__ __launch_bounds__(256) void final_ln_heads_kernel(
    const ushort_t* __restrict__ xb,
    const ushort_t* __restrict__ aggA, const ushort_t* __restrict__ aggB,
    float* __restrict__ out_x,
    const float* __restrict__ Wcls, const float* __restrict__ bcls,
    const float* __restrict__ Wdiff, const float* __restrict__ bdiff,
    const float* __restrict__ Wpre,
    float* __restrict__ mastery, float* __restrict__ diff,
    float* __restrict__ h1, float* __restrict__ h2,
    float* __restrict__ xp)
{
  __shared__ float sp4[4][512];
  const int w = threadIdx.x >> 6, lane = threadIdx.x & 63;
  const long row = (long)blockIdx.x * 4 + w;
  const long base = row * 512;
  float v[8];
  float s = 0.f;
#pragma unroll
  for (int k = 0; k < 8; ++k) {
    long idx = base + lane + 64 * k;
    v[k] = b2f(xb[idx]) + b2f(aggA[idx]) + b2f(aggB[idx]);
    s += v[k];
  }
#pragma unroll
  for (int msk = 1; msk <= 32; msk <<= 1) s += __shfl_xor(s, msk);
  float mean = s * (1.f / 512.f);
  float vv = 0.f;
#pragma unroll
  for (int k = 0; k < 8; ++k) { float d = v[k] - mean; vv += d * d; }
#pragma unroll
  for (int msk = 1; msk <= 32; msk <<= 1) vv += __shfl_xor(vv, msk);
  float inv = rsqrtf(vv * (1.f / 512.f) + 1e-5f);
#pragma unroll
  for (int k = 0; k < 8; ++k) {
    v[k] = (v[k] - mean) * inv;
    out_x[base + lane + 64 * k] = v[k];
    sp4[w][lane + 64 * k] = v[k];
  }
  __syncthreads();
  // block pool partial: sum of this block's 4 rows (256 blocks/batch)
  for (int t = threadIdx.x; t < 512; t += 256)
    xp[(long)blockIdx.x * 512 + t] =
        sp4[0][t] + sp4[1][t] + sp4[2][t] + sp4[3][t];
#pragma unroll
  for (int o = 0; o < 8; ++o) {
    const float* wp = (o == 0) ? Wcls
                    : (o <= 5) ? (Wdiff + (o - 1) * 512)
                    : (o == 6) ? Wpre : (Wpre + 512);
    float p = 0.f;
#pragma unroll
    for (int k = 0; k < 8; ++k) p += v[k] * wp[lane + 64 * k];
#pragma unroll
    for (int msk = 1; msk <= 32; msk <<= 1) p += __shfl_xor(p, msk);
    if (lane == 0) {
      if (o == 0)      mastery[row] = p + bcls[0];
      else if (o <= 5) diff[row * 5 + (o - 1)] = p + bdiff[o - 1];
      else if (o == 6) h1[row] = p;
      else             h2[row] = p;
    }
  }
}

// =========================================================================
// epilogue: [0,8184) prereq as flat aligned float4 stream
//   (t = b*1047552 + i*1023 + pos; i,pos via const-div; j = pos + (pos>=i)),
// [8184,8248) xq partial pool reduce: xq[b*8+qg][c] = sum of 32 xp rows.
// =========================================================================
__global__ __launch_bounds__(256) void epi_kernel(
    const float* __restrict__ h1, const float* __restrict__ h2,
    const float* __restrict__ bpre, float* __restrict__ outp,
    const float* __restrict__ xp, float* __restrict__ xq)
{
  const int bid = blockIdx.x;
  if (bid < 8184) {
    const int g = bid * 256 + threadIdx.x;
    const int t = g * 4;                     // global fp32 index, 16B aligned
    const int b = t / 1047552;               // 1024*1023
    const int r = t - b * 1047552;
    const float bp = bpre[0];
    const float* h1b = h1 + b * 1024;
    const float* h2b = h2 + b * 1024;
    floatx4 o;
#pragma unroll
    for (int k = 0; k < 4; ++k) {
      int rk = r + k;                        // stays within batch (1047552%4==0)
      int i = rk / 1023;
      int pos = rk - i * 1023;
      int j = pos + (pos >= i);
      o[k] = h1b[i] + bp + h2b[j];
    }
    *(floatx4*)(outp + t) = o;
  } else {
    const int q0 = bid - 8184;               // (b,qg): b=q0>>3, qg=q0&7
    const float* p = xp + (long)q0 * 32 * 512;
#pragma unroll
    for (int cc = 0; cc < 2; ++cc) {
      int c = threadIdx.x + cc * 256;
      float s = 0.f;
#pragma unroll
      for (int q = 0; q < 32; ++q) s += p[q * 512 + c];
      xq[(long)q0 * 512 + c] = s;
    }
  }
}

// graph[b,o] = (sum_p xq[b*8+p][:]/1024) . WpT[:,o] + b_pool[o]
// 8 blocks x 256 thr; WpT access coalesced across lanes, xms LDS broadcast.
__global__ __launch_bounds__(256) void graph_kernel(
    const float* __restrict__ xq, const float* __restrict__ WpT,
    const float* __restrict__ bpool, float* __restrict__ g)
{
  __shared__ float xms[512];
  const int b = blockIdx.x;
  const float* xb = xq + (long)b * 8 * 512;
#pragma unroll
  for (int cc = 0; cc < 2; ++cc) {
    int c = threadIdx.x + cc * 256;
    float s = 0.f;
#pragma unroll
    for (int p = 0; p < 8; ++p) s += xb[p * 512 + c];
    xms[c] = s;
  }
  __syncthreads();
#pragma unroll
  for (int oo = 0; oo < 2; ++oo) {
    int o = threadIdx.x + oo * 256;
    float acc = 0.f;
    for (int h = 0; h < 512; ++h) acc += xms[h] * WpT[h * 512 + o];
    g[b * 512 + o] = acc * (1.f / 1024.f) + bpool[o];
  }
}

// =========================================================================
extern "C" void kernel_launch(void* const* d_in, const int* in_sizes, int n_in,
                              void* d_out, int out_size, void* d_ws, size_t ws_size,
                              hipStream_t stream)
{
  const float* CF    = (const float*)d_in[0];
  const float* ADJ   = (const float*)d_in[1];
  const float* Wemb  = (const float*)d_in[4];
  const float* bemb  = (const float*)d_in[5];
  const float* Win   = (const float*)d_in[6];
  const float* bin   = (const float*)d_in[7];
  const float* Wout  = (const float*)d_in[8];
  const float* bout  = (const float*)d_in[9];
  const float* Wconv = (const float*)d_in[10];
  const float* bconv = (const float*)d_in[11];
  const float* Wcls  = (const float*)d_in[12];
  const float* bcls  = (const float*)d_in[13];
  const float* Wdiff = (const float*)d_in[14];
  const float* bdiff = (const float*)d_in[15];
  const float* Wpre  = (const float*)d_in[16];
  const float* bpre  = (const float*)d_in[17];
  const float* Wpool = (const float*)d_in[18];
  const float* bpool = (const float*)d_in[19];

  // ---- workspace layout (ushort units). Total ~72 MB (< proven 84 MB). ----
  ushort_t* W = (ushort_t*)d_ws;
  ushort_t* xb   = W;                       // 4194304
  ushort_t* qkvb = W + 4194304;             // 12582912 (end 16777216)
  // aliases inside the qkv region (dead when their user runs):
  ushort_t* cT    = qkvb;                   // 4194304 (conv out, post-attn)
  ushort_t* aggA  = qkvb + 4194304;         // 4194304 (split-K part 0)
  ushort_t* aggB  = qkvb + 8388608;         // 4194304 (split-K part 1)
  // precompute scratch overlays aggA/B region (dead before qkv0 GEMM):
  ushort_t* WoT   = qkvb + 4194304;         // 786432
  ushort_t* Wcb   = qkvb + 4980736;         // 786432
  ushort_t* WembT = qkvb + 5767168;         // 131072 (end 5898240 < 8388608)
  // persistent:
  ushort_t* Winb = W + 16777216;            // 2359296
  ushort_t* Wfb  = W + 19136512;            // 786432 (fused Wconv@Wout)
  ushort_t* ADJb = W + 19922944;            // 8388608 (end 28311552)
  ushort_t* CFb  = W + 28311552;            // 4194304 (end 32505856)
  ushort_t* Wq0  = W + 32505856;            // 524288 (rows 0-511 Wemb, 512-2047 Win0@Wemb)
  float* bfused = (float*)(W + 33030144);   // 1536
  float* bcat   = bfused + 1536;            // 2048 (bemb ++ folded qkv0 bias)
  float* h1     = bcat + 2048;              // 8192
  float* h2     = h1 + 8192;                // 8192
  float* xp     = h2 + 8192;                // 1048576 (pool partials, 2048x512)
  float* xq     = xp + 1048576;             // 32768  (pool partials, 64x512)
  float* WpT    = xq + 32768;               // 262144 (Wpool transposed, fp32)

  // ---- output layout (fp32 concat) + d_out-as-scratch aliases ----
  float* out_x       = (float*)d_out;       // 4194304
  float* out_mastery = out_x + 4194304;     // 8192
  float* out_diff    = out_mastery + 8192;  // 40960
  float* out_prereq  = out_diff + 40960;    // 8380416
  float* out_graph   = out_prereq + 8380416;// 4096
  // attn-out bf16 scratch in out_x region (dead before final LN writes it):
  ushort_t* aob = (ushort_t*)out_x;         // 4194304 ushorts

  dim3 blk(256);

  // ---- precompute: one dispatch + one merged setup-GEMM dispatch ----
  prep_kernel<<<dim3(7778), blk, 0, stream>>>(
      Win, Winb, Wemb, Wq0, Wconv, Wcb, ADJ, ADJb, CF, CFb,
      Wout, WoT, bout, bconv, bfused, WembT, bemb, bin, bcat,
      Wpool, WpT);
  setup_gemm<<<dim3(24, 1, 4), blk, 0, stream>>>(
      Wcb, WoT, Wfb, Winb, WembT, Wq0 + 512 * 256);

  for (int l = 0; l < 3; ++l) {
    // qkv = x @ Win[l]^T + bin[l]
    if (l == 0) {
      // fused x0|qkv0: [xb | qkvb] = CFb @ Wq0^T + bcat  (8192 x 2048 x 256)
      gemm_bt<3, 1><<<dim3(16, 64, 1), blk, 0, stream>>>(
          CFb, Wq0, bcat, xb, qkvb, 2048, 256, 0, 0, 0);
    } else {
      gemm_bt<1, 1><<<dim3(12, 64, 1), blk, 0, stream>>>(
          xb, Winb + (long)l * 786432, bin + l * 1536,
          qkvb, nullptr, 1536, 512, 0, 0, 0);
    }
    // attention over batch axis -> aob (out_x scratch)
    attn_kernel<<<dim3(1024), dim3(512), 0, stream>>>(qkvb, aob);
    // convT = (ao @ Wfused[l]^T + bfused[l]) transposed (qkv region dead)
    gemm_bt<2, 1><<<dim3(4, 64, 1), blk, 0, stream>>>(
        aob, Wfb + (long)l * 262144, bfused + l * 512,
        cT, nullptr, 512, 512, 0, 0, 0);
    // agg[b] = adj[b] @ conv[b]  (batched 1024x512x1024, split-K=2, bf16)
    gemm_bt<1, 2><<<dim3(4, 8, 16), blk, 0, stream>>>(
        ADJb, cT, nullptr, aggA, aggB,
        512, 1024, 1048576, 524288, 524288);
    // x = LN(x + aggA + aggB)
    if (l < 2)
      ln_kernel<<<dim3(2048), blk, 0, stream>>>(xb, aggA, aggB, xb);
    else
      final_ln_heads_kernel<<<dim3(2048), blk, 0, stream>>>(
          xb, aggA, aggB, out_x, Wcls, bcls, Wdiff, bdiff, Wpre,
          out_mastery, out_diff, h1, h2, xp);
  }

  epi_kernel<<<dim3(8248), blk, 0, stream>>>(h1, h2, bpre, out_prereq,
                                             xp, xq);
  graph_kernel<<<dim3(8), blk, 0, stream>>>(xq, WpT, bpool, out_graph);
}

// Round 5
// 420.822 us; speedup vs baseline: 1.0909x; 1.0059x over previous
//
#include <hip/hip_runtime.h>
#include <hip/hip_bf16.h>

typedef unsigned short ushort_t;
typedef __attribute__((ext_vector_type(4))) float floatx4;
typedef __attribute__((ext_vector_type(8))) __bf16 bf16x8;
typedef __attribute__((ext_vector_type(4))) unsigned short ushortx4;
typedef __attribute__((ext_vector_type(8))) unsigned short ushortx8;

// ---------- bf16 helpers ----------
static __device__ __forceinline__ float b2f(ushort_t u) {
  union { unsigned int i; float f; } v; v.i = ((unsigned int)u) << 16; return v.f;
}
static __device__ __forceinline__ ushort_t f2b(float f) {
  unsigned int x = __float_as_uint(f);
  unsigned int r = (x + 0x7fffu + ((x >> 16) & 1u)) >> 16;
  return (ushort_t)r;
}
// async global->LDS, 16B per lane (dest = wave-uniform base + lane*16)
static __device__ __forceinline__ void glds16(const ushort_t* g, ushort_t* l) {
  __builtin_amdgcn_global_load_lds(
      (const __attribute__((address_space(1))) unsigned int*)g,
      (__attribute__((address_space(3))) unsigned int*)l, 16, 0, 0);
}

// =========================================================================
// gemm8p: 256x256 tile, 8 waves (512 thr), double-buffered LDS (128 KB),
// counted-vmcnt phased schedule (T2+T3+T4+T5).  C[M,N] = A@B^T (+bias).
// Wave split 1M x 8N: per-wave output 256x32 (16 m-frags x 2 n-frags).
// Per K-tile (BK=64): 4 phases = (A-half ah, k-half kc); B-frags resident.
// Staging of tile t+1 spread across tile t's phases, order A0,B0,B1,A1:
//   q0: vmcnt(2) [cur A1 may fly] + barrier; read B(all)+A0/kc0; stage A0'
//   q1: read A0/kc1; stage B0'
//   q2: vmcnt(4) [drain cur A1; keep A0',B0'] + barrier; read A1/kc0; stage B1'
//   q3: read A1/kc1; stage A1'
// k-chunk XOR swizzle (slot c holds chunk c^(row&7)) -> conflict-free reads.
// MODE 1: bf16 row-major [M,N].  MODE 3: split-N x0|qkv0 (boundary 512).
// Accumulation order per acc = kc0 then kc1 per tile (same as 128q path).
// =========================================================================
template<int MODE>
__global__ __launch_bounds__(512, 2) void gemm8p(
    const ushort_t* __restrict__ Ab, const ushort_t* __restrict__ Bm,
    const float* __restrict__ bias,
    ushort_t* __restrict__ C0, ushort_t* __restrict__ C1,
    int N, int K)
{
  __shared__ __align__(16) ushort_t As[2 * 16384];
  __shared__ __align__(16) ushort_t Bs[2 * 16384];
  const int tid  = threadIdx.x;
  const int wid  = tid >> 6;    // 0..7, N-split
  const int lane = tid & 63;
  const int quad = lane >> 4;
  const int l16  = lane & 15;
  const int rx   = l16 & 7;
  const int lin = blockIdx.y * gridDim.x + blockIdx.x;
  const int m0 = (lin % gridDim.y) * 256;
  const int n0 = (lin / gridDim.y) * 256;
  const int NT = K >> 6;

  const int srow = tid >> 3;                  // 0..63
  const int scj  = ((tid & 7) ^ (srow & 7)) * 8;
  const long abase = (long)(m0 + srow) * K + scj;
  const long bbase = (long)(n0 + srow) * K + scj;

  floatx4 acc[16][2];
#pragma unroll
  for (int i = 0; i < 16; ++i) {
    acc[i][0] = (floatx4){0.f, 0.f, 0.f, 0.f};
    acc[i][1] = (floatx4){0.f, 0.f, 0.f, 0.f};
  }

#define STG_A(bf, h, t) do { const long k0_ = (long)(t) << 6; \
    glds16(Ab + abase + (long)((h) * 128     ) * K + k0_, &As[(bf) * 16384 + (h) * 8192 + tid * 8]); \
    glds16(Ab + abase + (long)((h) * 128 + 64) * K + k0_, &As[(bf) * 16384 + (h) * 8192 + 4096 + tid * 8]); } while (0)
#define STG_B(bf, h, t) do { const long k0_ = (long)(t) << 6; \
    glds16(Bm + bbase + (long)((h) * 128     ) * K + k0_, &Bs[(bf) * 16384 + (h) * 8192 + tid * 8]); \
    glds16(Bm + bbase + (long)((h) * 128 + 64) * K + k0_, &Bs[(bf) * 16384 + (h) * 8192 + 4096 + tid * 8]); } while (0)

  // prologue: tile 0, order A0,B0,B1,A1 (A1 newest -> q0's vmcnt(2) is exact)
  STG_A(0, 0, 0); STG_B(0, 0, 0); STG_B(0, 1, 0); STG_A(0, 1, 0);

  for (int t = 0; t < NT; ++t) {
    const int c = t & 1;
    const ushort_t* AsC = &As[c * 16384];
    const ushort_t* BsC = &Bs[c * 16384];
    const bool pf = (t + 1 < NT);
    bf16x8 a[8];
    bf16x8 bfr[2][2];

    // ---- q0 (ah=0, kc=0) ----
    asm volatile("s_waitcnt vmcnt(2)" ::: "memory");
    __builtin_amdgcn_s_barrier();
#pragma unroll
    for (int j = 0; j < 2; ++j)
#pragma unroll
      for (int kc = 0; kc < 2; ++kc)
        bfr[j][kc] = *(const bf16x8*)(&BsC[(wid * 32 + j * 16 + l16) * 64 +
                                           (((kc * 4 + quad) ^ rx) << 3)]);
#pragma unroll
    for (int f = 0; f < 8; ++f)
      a[f] = *(const bf16x8*)(&AsC[(f * 16 + l16) * 64 + ((quad ^ rx) << 3)]);
    if (pf) STG_A(c ^ 1, 0, t + 1);
    __builtin_amdgcn_s_setprio(1);
#pragma unroll
    for (int f = 0; f < 8; ++f) {
      acc[f][0] = __builtin_amdgcn_mfma_f32_16x16x32_bf16(a[f], bfr[0][0], acc[f][0], 0, 0, 0);
      acc[f][1] = __builtin_amdgcn_mfma_f32_16x16x32_bf16(a[f], bfr[1][0], acc[f][1], 0, 0, 0);
    }
    __builtin_amdgcn_s_setprio(0);

    // ---- q1 (ah=0, kc=1) ----
#pragma unroll
    for (int f = 0; f < 8; ++f)
      a[f] = *(const bf16x8*)(&AsC[(f * 16 + l16) * 64 + (((4 + quad) ^ rx) << 3)]);
    if (pf) STG_B(c ^ 1, 0, t + 1);
    __builtin_amdgcn_s_setprio(1);
#pragma unroll
    for (int f = 0; f < 8; ++f) {
      acc[f][0] = __builtin_amdgcn_mfma_f32_16x16x32_bf16(a[f], bfr[0][1], acc[f][0], 0, 0, 0);
      acc[f][1] = __builtin_amdgcn_mfma_f32_16x16x32_bf16(a[f], bfr[1][1], acc[f][1], 0, 0, 0);
    }
    __builtin_amdgcn_s_setprio(0);

    // ---- q2 (ah=1, kc=0) ----
    if (pf) { asm volatile("s_waitcnt vmcnt(4)" ::: "memory"); }
    else    { asm volatile("s_waitcnt vmcnt(0)" ::: "memory"); }
    __builtin_amdgcn_s_barrier();
#pragma unroll
    for (int f = 0; f < 8; ++f)
      a[f] = *(const bf16x8*)(&AsC[(128 + f * 16 + l16) * 64 + ((quad ^ rx) << 3)]);
    if (pf) STG_B(c ^ 1, 1, t + 1);
    __builtin_amdgcn_s_setprio(1);
#pragma unroll
    for (int f = 0; f < 8; ++f) {
      acc[8 + f][0] = __builtin_amdgcn_mfma_f32_16x16x32_bf16(a[f], bfr[0][0], acc[8 + f][0], 0, 0, 0);
      acc[8 + f][1] = __builtin_amdgcn_mfma_f32_16x16x32_bf16(a[f], bfr[1][0], acc[8 + f][1], 0, 0, 0);
    }
    __builtin_amdgcn_s_setprio(0);

    // ---- q3 (ah=1, kc=1) ----
#pragma unroll
    for (int f = 0; f < 8; ++f)
      a[f] = *(const bf16x8*)(&AsC[(128 + f * 16 + l16) * 64 + (((4 + quad) ^ rx) << 3)]);
    if (pf) STG_A(c ^ 1, 1, t + 1);
    __builtin_amdgcn_s_setprio(1);
#pragma unroll
    for (int f = 0; f < 8; ++f) {
      acc[8 + f][0] = __builtin_amdgcn_mfma_f32_16x16x32_bf16(a[f], bfr[0][1], acc[8 + f][0], 0, 0, 0);
      acc[8 + f][1] = __builtin_amdgcn_mfma_f32_16x16x32_bf16(a[f], bfr[1][1], acc[8 + f][1], 0, 0, 0);
    }
    __builtin_amdgcn_s_setprio(0);
  }
#undef STG_A
#undef STG_B

  // epilogue
#pragma unroll
  for (int fj = 0; fj < 2; ++fj) {
    int col = n0 + wid * 32 + fj * 16 + l16;
    float bv = (bias != nullptr) ? bias[col] : 0.f;
#pragma unroll
    for (int fi = 0; fi < 16; ++fi) {
      int mbase = m0 + fi * 16 + quad * 4;
      if constexpr (MODE == 1) {
#pragma unroll
        for (int r = 0; r < 4; ++r)
          C0[(long)(mbase + r) * N + col] = f2b(acc[fi][fj][r] + bv);
      } else {
        // MODE 3: split-N (n-tiles 256-wide never straddle col 512)
        ushort_t* o = (n0 < 512) ? C0 : C1;
        const int cw = (n0 < 512) ? 512 : 1536;
        const int cc = (n0 < 512) ? col : col - 512;
#pragma unroll
        for (int r = 0; r < 4; ++r)
          o[(long)(mbase + r) * cw + cc] = f2b(acc[fi][fj][r] + bv);
      }
    }
  }
}

// =========================================================================
// GEMM core (128x128 tile, 4 waves): C = A@B^T (+bias). Used for the
// smaller shapes (setup, conv, agg) where 256q tiles would underfill.
// MODE 1: bf16 row-major.  MODE 2: bf16 transposed batched.
// =========================================================================
template<int MODE>
static __device__ __forceinline__ void gemm_core(
    const ushort_t* __restrict__ Ab, const ushort_t* __restrict__ Bm,
    const float* __restrict__ bias,
    ushort_t* __restrict__ outB, ushort_t* __restrict__ C1,
    int N, int K, int m0, int n0, int kbeg, int kend,
    ushort_t* As, ushort_t* Bs)
{
  const int tid  = threadIdx.x;
  const int wid  = tid >> 6;
  const int lane = tid & 63;
  const int quad = lane >> 4;
  const int l16  = lane & 15;

  const int wr = (wid >> 1) * 64;
  const int wc = (wid & 1) * 64;

  const int srow = tid >> 3;
  const int scj  = ((tid & 7) ^ (srow & 7)) * 8;
  const long abase = (long)(m0 + srow) * K + scj;
  const long bbase = (long)(n0 + srow) * K + scj;

  floatx4 acc[4][4];
#pragma unroll
  for (int i = 0; i < 4; ++i)
#pragma unroll
    for (int j = 0; j < 4; ++j) acc[i][j] = (floatx4){0.f, 0.f, 0.f, 0.f};

  const int rx = l16 & 7;

  for (int k0 = kbeg; k0 < kend; k0 += 64) {
    __syncthreads();
#pragma unroll
    for (int p = 0; p < 4; ++p)
      glds16(Ab + abase + 32 * p * (long)K + k0, &As[tid * 8 + p * 2048]);
#pragma unroll
    for (int p = 0; p < 4; ++p)
      glds16(Bm + bbase + 32 * p * (long)K + k0, &Bs[tid * 8 + p * 2048]);
    __syncthreads();

#pragma unroll
    for (int kk = 0; kk < 2; ++kk) {
      bf16x8 a[4], b[4];
#pragma unroll
      for (int i = 0; i < 4; ++i)
        a[i] = *(const bf16x8*)(&As[(wr + i * 16 + l16) * 64 +
                                    (((kk * 4 + quad) ^ rx) << 3)]);
#pragma unroll
      for (int j = 0; j < 4; ++j)
        b[j] = *(const bf16x8*)(&Bs[(wc + j * 16 + l16) * 64 +
                                    (((kk * 4 + quad) ^ rx) << 3)]);
#pragma unroll
      for (int i = 0; i < 4; ++i)
#pragma unroll
        for (int j = 0; j < 4; ++j)
          acc[i][j] = __builtin_amdgcn_mfma_f32_16x16x32_bf16(a[i], b[j], acc[i][j], 0, 0, 0);
    }
  }

#pragma unroll
  for (int j = 0; j < 4; ++j) {
    int col = n0 + wc + j * 16 + l16;
    float bv = (bias != nullptr) ? bias[col] : 0.f;
#pragma unroll
    for (int i = 0; i < 4; ++i) {
      int mbase = m0 + wr + i * 16 + quad * 4;
      if constexpr (MODE == 1) {
#pragma unroll
        for (int r = 0; r < 4; ++r)
          outB[(long)(mbase + r) * N + col] = f2b(acc[i][j][r] + bv);
      } else {
        int b = mbase >> 10, jrow = mbase & 1023;
        ushortx4 pk;
#pragma unroll
        for (int r = 0; r < 4; ++r) pk[r] = f2b(acc[i][j][r] + bv);
        *(ushortx4*)(outB + ((long)b * N + col) * 1024 + jrow) = pk;
      }
    }
  }
}

// generic dispatcher: XCD swizzle lin = y*gridX+x; m = lin%gridY, n = lin/gridY
// KS: split-K ways; blockIdx.z = z*KS+kq; partial kq -> C{kq}.
template<int MODE, int KS>
__global__ __launch_bounds__(256, 3) void gemm_bt(
    const ushort_t* __restrict__ Ab, const ushort_t* __restrict__ Bm,
    const float* __restrict__ bias,
    ushort_t* __restrict__ C0, ushort_t* __restrict__ C1,
    int N, int K, long aBatch, long bBatch, long cBatch)
{
  __shared__ __align__(16) ushort_t As[128 * 64];
  __shared__ __align__(16) ushort_t Bs[128 * 64];
  const int lin = blockIdx.y * gridDim.x + blockIdx.x;
  const int m0 = (lin % gridDim.y) * 128;
  const int n0 = (lin / gridDim.y) * 128;
  const int z  = (KS > 1) ? (int)(blockIdx.z / KS) : blockIdx.z;
  const int kq = (KS > 1) ? (int)(blockIdx.z % KS) : 0;
  const int kbeg = kq * (K / KS);
  const int kend = kbeg + (K / KS);
  ushort_t* outB = (KS >= 2 && kq == 1) ? C1 : C0;
  gemm_core<MODE>(Ab + (long)z * aBatch, Bm + (long)z * bBatch, bias,
                  outB + ((MODE == 1) ? (long)z * cBatch : 0), C1,
                  N, K, m0, n0, kbeg, kend, As, Bs);
}

// setup GEMMs merged: z<3 -> Wfused[z] = Wconv[z] @ Wout[z] (512x512x512);
// z==3 -> Wq0 tail = Win0 @ Wemb (1536x256x512). Grid (24,1,4).
__global__ __launch_bounds__(256, 3) void setup_gemm(
    const ushort_t* __restrict__ Wcb, const ushort_t* __restrict__ WoT,
    ushort_t* __restrict__ Wfb,
    const ushort_t* __restrict__ Winb, const ushort_t* __restrict__ WembT,
    ushort_t* __restrict__ Wq0t)
{
  __shared__ __align__(16) ushort_t As[128 * 64];
  __shared__ __align__(16) ushort_t Bs[128 * 64];
  const int lin = blockIdx.x;
  const int z = blockIdx.z;
  if (z < 3) {
    if (lin >= 16) return;   // block-uniform exit, before any barrier
    const long off = (long)z * 262144;
    gemm_core<1>(Wcb + off, WoT + off, nullptr, Wfb + off, nullptr,
                 512, 512, (lin & 3) * 128, (lin >> 2) * 128, 0, 512, As, Bs);
  } else {
    gemm_core<1>(Winb, WembT, nullptr, Wq0t, nullptr,
                 256, 512, (lin % 12) * 128, (lin / 12) * 128, 0, 512, As, Bs);
  }
}

// =========================================================================
// prep (one dispatch): fp32->bf16 conversions (Win, Wemb->Wq0 head, Wconv,
// ADJ, CF), Wout transpose, Wemb transpose, bfused, folded layer-0 bias,
// Wpool fp32 transpose.
// =========================================================================
__global__ __launch_bounds__(256) void prep_kernel(
    const float* __restrict__ Win,  ushort_t* __restrict__ Winb,
    const float* __restrict__ Wemb, ushort_t* __restrict__ Wq0,
    const float* __restrict__ Wconv, ushort_t* __restrict__ Wcb,
    const float* __restrict__ ADJ,  ushort_t* __restrict__ ADJb,
    const float* __restrict__ CF,   ushort_t* __restrict__ CFb,
    const float* __restrict__ Wout, ushort_t* __restrict__ WoT,
    const float* __restrict__ bout, const float* __restrict__ bconv,
    float* __restrict__ bfused,
    ushort_t* __restrict__ WembT,
    const float* __restrict__ bemb, const float* __restrict__ bin0,
    float* __restrict__ bcat,
    const float* __restrict__ Wpool, float* __restrict__ WpT)
{
  __shared__ float tile[64][65];
  const int bid = blockIdx.x, tid = threadIdx.x;
  if (bid < 6720) {
    const float* src; ushort_t* dst; long i;
    if (bid < 1152)      { src = Win;   dst = Winb; i = (long)bid * 256 + tid; }
    else if (bid < 1216) { src = Wemb;  dst = Wq0;  i = (long)(bid - 1152) * 256 + tid; }
    else if (bid < 1600) { src = Wconv; dst = Wcb;  i = (long)(bid - 1216) * 256 + tid; }
    else if (bid < 5696) { src = ADJ;   dst = ADJb; i = (long)(bid - 1600) * 256 + tid; }
    else                 { src = CF;    dst = CFb;  i = (long)(bid - 5696) * 256 + tid; }
    floatx4 a = ((const floatx4*)src)[2 * i];
    floatx4 b = ((const floatx4*)src)[2 * i + 1];
    ushortx4 ha, hb;
#pragma unroll
    for (int r = 0; r < 4; ++r) { ha[r] = f2b(a[r]); hb[r] = f2b(b[r]); }
    ((ushortx4*)dst)[2 * i] = ha; ((ushortx4*)dst)[2 * i + 1] = hb;
  } else if (bid < 6912) {
    // transpose+cvt: T[l][k][j] = bf16(Wout[l][j][k])
    const int t = bid - 6720;
    const int z = t >> 6, k0 = ((t >> 3) & 7) * 64, j0 = (t & 7) * 64;
    const long base = (long)z * 262144;
#pragma unroll
    for (int p = 0; p < 16; ++p) {
      int idx = tid + p * 256;
      int jj = idx >> 6, kk = idx & 63;
      tile[jj][kk] = Wout[base + (long)(j0 + jj) * 512 + k0 + kk];
    }
    __syncthreads();
#pragma unroll
    for (int p = 0; p < 16; ++p) {
      int idx = tid + p * 256;
      int kk = idx >> 6, jj = idx & 63;
      WoT[base + (long)(k0 + kk) * 512 + j0 + jj] = f2b(tile[jj][kk]);
    }
  } else if (bid < 6944) {
    // WembT[c][h] = bf16(Wemb[h][c])  (Wemb is [512][256])
    const int t = bid - 6912;
    const int j0 = (t >> 2) * 64, k0 = (t & 3) * 64;
#pragma unroll
    for (int p = 0; p < 16; ++p) {
      int idx = tid + p * 256;
      int jj = idx >> 6, kk = idx & 63;
      tile[jj][kk] = Wemb[(long)(j0 + jj) * 256 + k0 + kk];
    }
    __syncthreads();
#pragma unroll
    for (int p = 0; p < 16; ++p) {
      int idx = tid + p * 256;
      int kk = idx >> 6, jj = idx & 63;
      WembT[(long)(k0 + kk) * 512 + j0 + jj] = f2b(tile[jj][kk]);
    }
  } else if (bid < 7328) {
    // bfused[l][o] = dot(Wconv[l][o][:], bout[l][:]) + bconv[l][o]
    const int w = tid >> 6, lane = tid & 63;
    const int gi = (bid - 6944) * 4 + w;
    const int l = gi >> 9, o = gi & 511;
    float p = 0.f;
#pragma unroll
    for (int k = 0; k < 8; ++k)
      p += Wconv[(long)l * 262144 + (long)o * 512 + lane + 64 * k] *
           bout[l * 512 + lane + 64 * k];
#pragma unroll
    for (int msk = 1; msk <= 32; msk <<= 1) p += __shfl_xor(p, msk);
    if (lane == 0) bfused[gi] = p + bconv[l * 512 + o];
  } else if (bid < 7712) {
    // bcat[512+o] = bin0[o] + dot(Win0[o][:], bemb[:])  (layer-0 bias fold)
    const int w = tid >> 6, lane = tid & 63;
    const int o = (bid - 7328) * 4 + w;
    float p = 0.f;
#pragma unroll
    for (int k = 0; k < 8; ++k)
      p += Win[(long)o * 512 + lane + 64 * k] * bemb[lane + 64 * k];
#pragma unroll
    for (int msk = 1; msk <= 32; msk <<= 1) p += __shfl_xor(p, msk);
    if (lane == 0) bcat[512 + o] = p + bin0[o];
  } else if (bid < 7714) {
    // bcat[0:512] = bemb
    int idx = (bid - 7712) * 256 + tid;
    bcat[idx] = bemb[idx];
  } else {
    // WpT[h][o] = Wpool[o][h]  (fp32, for coalesced graph dot)
    const int t = bid - 7714;
    const int j0 = (t >> 3) * 64, k0 = (t & 7) * 64;
#pragma unroll
    for (int p = 0; p < 16; ++p) {
      int idx = tid + p * 256;
      int jj = idx >> 6, kk = idx & 63;
      tile[jj][kk] = Wpool[(long)(j0 + jj) * 512 + k0 + kk];
    }
    __syncthreads();
#pragma unroll
    for (int p = 0; p < 16; ++p) {
      int idx = tid + p * 256;
      int kk = idx >> 6, jj = idx & 63;
      WpT[(long)(k0 + kk) * 512 + j0 + jj] = tile[jj][kk];
    }
  }
}

// =========================================================================
// Attention over batch axis. Block (512 thr) per node n; qkv staged in LDS
// as bf16; wave = head; stride 1544.
// =========================================================================
__global__ __launch_bounds__(512, 8) void attn_kernel(
    const ushort_t* __restrict__ qkv, ushort_t* __restrict__ outp)
{
  __shared__ ushort_t qs[8 * 1544];
  __shared__ float aw[8][64];
  const int tid = threadIdx.x;
  const int n = blockIdx.x;

  const ushort_t* src = qkv + (long)n * 1536;
#pragma unroll
  for (int p = 0; p < 3; ++p) {
    int c = tid + p * 512;
    int i = c / 192, off = (c % 192) * 8;
    *(ushortx8*)(&qs[i * 1544 + off]) =
        *(const ushortx8*)(src + (long)i * 1024 * 1536 + off);
  }
  __syncthreads();

  const int h    = tid >> 6;
  const int lane = tid & 63;
  const int i = lane >> 3, j = lane & 7;
  const ushort_t* qrow = &qs[i * 1544 + h * 64];
  const ushort_t* krow = &qs[j * 1544 + 512 + h * 64];
  float s = 0.f;
#pragma unroll
  for (int c8 = 0; c8 < 8; ++c8) {
    ushortx8 qa = *(const ushortx8*)(qrow + c8 * 8);
    ushortx8 ka = *(const ushortx8*)(krow + c8 * 8);
#pragma unroll
    for (int r = 0; r < 8; ++r) s += b2f(qa[r]) * b2f(ka[r]);
  }
  s *= 0.125f;

  float m = s;
  m = fmaxf(m, __shfl_xor(m, 1));
  m = fmaxf(m, __shfl_xor(m, 2));
  m = fmaxf(m, __shfl_xor(m, 4));
  float e = __expf(s - m);
  float sum = e;
  sum += __shfl_xor(sum, 1);
  sum += __shfl_xor(sum, 2);
  sum += __shfl_xor(sum, 4);
  aw[h][lane] = e / sum;   // written+read by the same wave; no barrier needed

  float vv[8];
#pragma unroll
  for (int jj = 0; jj < 8; ++jj)
    vv[jj] = b2f(qs[jj * 1544 + 1024 + h * 64 + lane]);
  const long ob = (long)n * 512 + h * 64 + lane;
#pragma unroll
  for (int ii = 0; ii < 8; ++ii) {
    float acc = 0.f;
#pragma unroll
    for (int jj = 0; jj < 8; ++jj) acc += aw[h][ii * 8 + jj] * vv[jj];
    outp[ob + (long)ii * 1024 * 512] = f2b(acc);
  }
}

// =========================================================================
// x_out(bf16) = LayerNorm(x + aggA+aggB). Wave per row (512).
// =========================================================================
__global__ __launch_bounds__(256) void ln_kernel(
    const ushort_t* __restrict__ xb,
    const ushort_t* __restrict__ aggA, const ushort_t* __restrict__ aggB,
    ushort_t* __restrict__ outB)
{
  const int w = threadIdx.x >> 6, lane = threadIdx.x & 63;
  const long base = ((long)blockIdx.x * 4 + w) * 512;
  float v[8];
  float s = 0.f;
#pragma unroll
  for (int k = 0; k < 8; ++k) {
    long idx = base + lane + 64 * k;
    v[k] = b2f(xb[idx]) + b2f(aggA[idx]) + b2f(aggB[idx]);
    s += v[k];
  }
#pragma unroll
  for (int msk = 1; msk <= 32; msk <<= 1) s += __shfl_xor(s, msk);
  float mean = s * (1.f / 512.f);
  float vv = 0.f;
#pragma unroll
  for (int k = 0; k < 8; ++k) { float d = v[k] - mean; vv += d * d; }
#pragma unroll
  for (int msk = 1; msk <= 32; msk <<= 1) vv += __shfl_xor(vv, msk);
  float inv = rsqrtf(vv * (1.f / 512.f) + 1e-5f);
#pragma unroll
  for (int k = 0; k < 8; ++k)
    outB[base + lane + 64 * k] = f2b((v[k] - mean) * inv);
}

// =========================================================================
// Final layer: LN -> out_x (fp32) + fused heads + pool partials xp.
// =========================================================================
__global__ __launch_bounds__(256) void final_ln_heads_kernel(
    const ushort_t* __restrict__ xb,
    const ushort_t* __restrict__ aggA, const ushort_t* __restrict__ aggB,
    float* __restrict__ out_x,
    const float* __restrict__ Wcls, const float* __restrict__ bcls,
    const float* __restrict__ Wdiff, const float* __restrict__ bdiff,
    const float* __restrict__ Wpre,
    float* __restrict__ mastery, float* __restrict__ diff,
    float* __restrict__ h1, float* __restrict__ h2,
    float* __restrict__ xp)
{
  __shared__ float sp4[4][512];
  const int w = threadIdx.x >> 6, lane = threadIdx.x & 63;
  const long row = (long)blockIdx.x * 4 + w;
  const long base = row * 512;
  float v[8];
  float s = 0.f;
#pragma unroll
  for (int k = 0; k < 8; ++k) {
    long idx = base + lane + 64 * k;
    v[k] = b2f(xb[idx]) + b2f(aggA[idx]) + b2f(aggB[idx]);
    s += v[k];
  }
#pragma unroll
  for (int msk = 1; msk <= 32; msk <<= 1) s += __shfl_xor(s, msk);
  float mean = s * (1.f / 512.f);
  float vv = 0.f;
#pragma unroll
  for (int k = 0; k < 8; ++k) { float d = v[k] - mean; vv += d * d; }
#pragma unroll
  for (int msk = 1; msk <= 32; msk <<= 1) vv += __shfl_xor(vv, msk);
  float inv = rsqrtf(vv * (1.f / 512.f) + 1e-5f);
#pragma unroll
  for (int k = 0; k < 8; ++k) {
    v[k] = (v[k] - mean) * inv;
    out_x[base + lane + 64 * k] = v[k];
    sp4[w][lane + 64 * k] = v[k];
  }
  __syncthreads();
  for (int t = threadIdx.x; t < 512; t += 256)
    xp[(long)blockIdx.x * 512 + t] =
        sp4[0][t] + sp4[1][t] + sp4[2][t] + sp4[3][t];
#pragma unroll
  for (int o = 0; o < 8; ++o) {
    const float* wp = (o == 0) ? Wcls
                    : (o <= 5) ? (Wdiff + (o - 1) * 512)
                    : (o == 6) ? Wpre : (Wpre + 512);
    float p = 0.f;
#pragma unroll
    for (int k = 0; k < 8; ++k) p += v[k] * wp[lane + 64 * k];
#pragma unroll
    for (int msk = 1; msk <= 32; msk <<= 1) p += __shfl_xor(p, msk);
    if (lane == 0) {
      if (o == 0)      mastery[row] = p + bcls[0];
      else if (o <= 5) diff[row * 5 + (o - 1)] = p + bdiff[o - 1];
      else if (o == 6) h1[row] = p;
      else             h2[row] = p;
    }
  }
}

// =========================================================================
// epilogue: [0,8184) prereq as flat aligned float4 stream,
// [8184,8248) xq partial pool reduce.
// =========================================================================
__global__ __launch_bounds__(256) void epi_kernel(
    const float* __restrict__ h1, const float* __restrict__ h2,
    const float* __restrict__ bpre, float* __restrict__ outp,
    const float* __restrict__ xp, float* __restrict__ xq)
{
  const int bid = blockIdx.x;
  if (bid < 8184) {
    const int g = bid * 256 + threadIdx.x;
    const int t = g * 4;
    const int b = t / 1047552;
    const int r = t - b * 1047552;
    const float bp = bpre[0];
    const float* h1b = h1 + b * 1024;
    const float* h2b = h2 + b * 1024;
    floatx4 o;
#pragma unroll
    for (int k = 0; k < 4; ++k) {
      int rk = r + k;
      int i = rk / 1023;
      int pos = rk - i * 1023;
      int j = pos + (pos >= i);
      o[k] = h1b[i] + bp + h2b[j];
    }
    *(floatx4*)(outp + t) = o;
  } else {
    const int q0 = bid - 8184;
    const float* p = xp + (long)q0 * 32 * 512;
#pragma unroll
    for (int cc = 0; cc < 2; ++cc) {
      int c = threadIdx.x + cc * 256;
      float s = 0.f;
#pragma unroll
      for (int q = 0; q < 32; ++q) s += p[q * 512 + c];
      xq[(long)q0 * 512 + c] = s;
    }
  }
}

// graph[b,o] = (sum_p xq[b*8+p][:]/1024) . WpT[:,o] + b_pool[o]
__global__ __launch_bounds__(256) void graph_kernel(
    const float* __restrict__ xq, const float* __restrict__ WpT,
    const float* __restrict__ bpool, float* __restrict__ g)
{
  __shared__ float xms[512];
  const int b = blockIdx.x;
  const float* xb = xq + (long)b * 8 * 512;
#pragma unroll
  for (int cc = 0; cc < 2; ++cc) {
    int c = threadIdx.x + cc * 256;
    float s = 0.f;
#pragma unroll
    for (int p = 0; p < 8; ++p) s += xb[p * 512 + c];
    xms[c] = s;
  }
  __syncthreads();
#pragma unroll
  for (int oo = 0; oo < 2; ++oo) {
    int o = threadIdx.x + oo * 256;
    float acc = 0.f;
    for (int h = 0; h < 512; ++h) acc += xms[h] * WpT[h * 512 + o];
    g[b * 512 + o] = acc * (1.f / 1024.f) + bpool[o];
  }
}

// =========================================================================
extern "C" void kernel_launch(void* const* d_in, const int* in_sizes, int n_in,
                              void* d_out, int out_size, void* d_ws, size_t ws_size,
                              hipStream_t stream)
{
  const float* CF    = (const float*)d_in[0];
  const float* ADJ   = (const float*)d_in[1];
  const float* Wemb  = (const float*)d_in[4];
  const float* bemb  = (const float*)d_in[5];
  const float* Win   = (const float*)d_in[6];
  const float* bin   = (const float*)d_in[7];
  const float* Wout  = (const float*)d_in[8];
  const float* bout  = (const float*)d_in[9];
  const float* Wconv = (const float*)d_in[10];
  const float* bconv = (const float*)d_in[11];
  const float* Wcls  = (const float*)d_in[12];
  const float* bcls  = (const float*)d_in[13];
  const float* Wdiff = (const float*)d_in[14];
  const float* bdiff = (const float*)d_in[15];
  const float* Wpre  = (const float*)d_in[16];
  const float* bpre  = (const float*)d_in[17];
  const float* Wpool = (const float*)d_in[18];
  const float* bpool = (const float*)d_in[19];

  // ---- workspace layout (ushort units). Total ~72 MB (< proven 84 MB). ----
  ushort_t* W = (ushort_t*)d_ws;
  ushort_t* xb   = W;                       // 4194304
  ushort_t* qkvb = W + 4194304;             // 12582912 (end 16777216)
  ushort_t* cT    = qkvb;                   // 4194304 (conv out, post-attn)
  ushort_t* aggA  = qkvb + 4194304;         // 4194304 (split-K part 0)
  ushort_t* aggB  = qkvb + 8388608;         // 4194304 (split-K part 1)
  ushort_t* WoT   = qkvb + 4194304;         // 786432
  ushort_t* Wcb   = qkvb + 4980736;         // 786432
  ushort_t* WembT = qkvb + 5767168;         // 131072 (end 5898240 < 8388608)
  ushort_t* Winb = W + 16777216;            // 2359296
  ushort_t* Wfb  = W + 19136512;            // 786432 (fused Wconv@Wout)
  ushort_t* ADJb = W + 19922944;            // 8388608 (end 28311552)
  ushort_t* CFb  = W + 28311552;            // 4194304 (end 32505856)
  ushort_t* Wq0  = W + 32505856;            // 524288
  float* bfused = (float*)(W + 33030144);   // 1536
  float* bcat   = bfused + 1536;            // 2048
  float* h1     = bcat + 2048;              // 8192
  float* h2     = h1 + 8192;                // 8192
  float* xp     = h2 + 8192;                // 1048576
  float* xq     = xp + 1048576;             // 32768
  float* WpT    = xq + 32768;               // 262144

  // ---- output layout (fp32 concat) + d_out-as-scratch aliases ----
  float* out_x       = (float*)d_out;       // 4194304
  float* out_mastery = out_x + 4194304;     // 8192
  float* out_diff    = out_mastery + 8192;  // 40960
  float* out_prereq  = out_diff + 40960;    // 8380416
  float* out_graph   = out_prereq + 8380416;// 4096
  ushort_t* aob = (ushort_t*)out_x;         // attn-out scratch

  dim3 blk(256);
  dim3 blk8(512);

  prep_kernel<<<dim3(7778), blk, 0, stream>>>(
      Win, Winb, Wemb, Wq0, Wconv, Wcb, ADJ, ADJb, CF, CFb,
      Wout, WoT, bout, bconv, bfused, WembT, bemb, bin, bcat,
      Wpool, WpT);
  setup_gemm<<<dim3(24, 1, 4), blk, 0, stream>>>(
      Wcb, WoT, Wfb, Winb, WembT, Wq0 + 512 * 256);

  for (int l = 0; l < 3; ++l) {
    if (l == 0) {
      // fused x0|qkv0: [xb | qkvb] = CFb @ Wq0^T + bcat  (8192 x 2048 x 256)
      gemm8p<3><<<dim3(8, 32), blk8, 0, stream>>>(
          CFb, Wq0, bcat, xb, qkvb, 2048, 256);
    } else {
      gemm8p<1><<<dim3(6, 32), blk8, 0, stream>>>(
          xb, Winb + (long)l * 786432, bin + l * 1536,
          qkvb, nullptr, 1536, 512);
    }
    // attention over batch axis -> aob (out_x scratch)
    attn_kernel<<<dim3(1024), dim3(512), 0, stream>>>(qkvb, aob);
    // convT = (ao @ Wfused[l]^T + bfused[l]) transposed (qkv region dead)
    gemm_bt<2, 1><<<dim3(4, 64, 1), blk, 0, stream>>>(
        aob, Wfb + (long)l * 262144, bfused + l * 512,
        cT, nullptr, 512, 512, 0, 0, 0);
    // agg[b] = adj[b] @ conv[b]  (batched 1024x512x1024, split-K=2, bf16)
    gemm_bt<1, 2><<<dim3(4, 8, 16), blk, 0, stream>>>(
        ADJb, cT, nullptr, aggA, aggB,
        512, 1024, 1048576, 524288, 524288);
    // x = LN(x + aggA + aggB)
    if (l < 2)
      ln_kernel<<<dim3(2048), blk, 0, stream>>>(xb, aggA, aggB, xb);
    else
      final_ln_heads_kernel<<<dim3(2048), blk, 0, stream>>>(
          xb, aggA, aggB, out_x, Wcls, bcls, Wdiff, bdiff, Wpre,
          out_mastery, out_diff, h1, h2, xp);
  }

  epi_kernel<<<dim3(8248), blk, 0, stream>>>(h1, h2, bpre, out_prereq,
                                             xp, xq);
  graph_kernel<<<dim3(8), blk, 0, stream>>>(xq, WpT, bpool, out_graph);
}